// Round 5
// baseline (443.096 us; speedup 1.0000x reference)
//
#include <hip/hip_runtime.h>
#include <hip/hip_bf16.h>

// Problem constants (from reference)
#define NN 50000
#define EE 100000
#define GG 2048
// D = 32 hidden, F_NODE = 11, F_EDGE = 4

// feat = relu(x @ lin0_w.T + lin0_b); thread per (node, out-dim)
__global__ void k_init(const float* __restrict__ x, const float* __restrict__ w,
                       const float* __restrict__ b, float* __restrict__ feat) {
    int idx = blockIdx.x * blockDim.x + threadIdx.x;
    if (idx >= NN * 32) return;
    int n = idx >> 5, o = idx & 31;
    const float* xr = x + n * 11;
    const float* wr = w + o * 11;
    float acc = b[o];
#pragma unroll
    for (int i = 0; i < 11; ++i) acc += xr[i] * wr[i];
    feat[idx] = fmaxf(acc, 0.f);
}

// Build rearranged weight tables:
//  Wre [c][i]  (160x32): c=f*32+o (f<4) from nn_w, c=128+o from nn_b
//  WreT[i][c]  (32x160): transpose of Wre (for coalesced per-lane reads)
//  wiT [k][c]  (32x96):  wiT[k*96+c] = gru_wi[c*32+k]
//  whT [k][c]  (32x96):  whT[k*96+c] = gru_wh[c*32+k]
__global__ void k_prep(const float* __restrict__ nnw, const float* __restrict__ nnb,
                       const float* __restrict__ wi, const float* __restrict__ wh,
                       float* __restrict__ Wre, float* __restrict__ WreT,
                       float* __restrict__ wiT, float* __restrict__ whT) {
    int idx = blockIdx.x * blockDim.x + threadIdx.x;
    if (idx < 5120) {
        int c = idx >> 5, i = idx & 31;
        float v;
        if (c < 128) v = nnw[((i << 5) + (c & 31)) * 4 + (c >> 5)];
        else         v = nnb[(i << 5) + (c - 128)];
        Wre[idx] = v;
    } else if (idx < 10240) {
        int j = idx - 5120;
        int i = j / 160, c = j - i * 160;
        float v;
        if (c < 128) v = nnw[((i << 5) + (c & 31)) * 4 + (c >> 5)];
        else         v = nnb[(i << 5) + (c - 128)];
        WreT[j] = v;
    } else if (idx < 13312) {
        int j = idx - 10240;
        int k = j / 96, c = j - k * 96;
        wiT[j] = wi[c * 32 + k];
    } else if (idx < 16384) {
        int j = idx - 13312;
        int k = j / 96, c = j - k * 96;
        whT[j] = wh[c * 32 + k];
    }
}

// y[n,c] = sum_i feat[n,i] * WreT[i*160+c].
// Block = 320 threads = 2 nodes x 160 cols; feat rows staged in LDS
// (broadcast reads); weight loads per-lane coalesced, table L1-resident.
__global__ __launch_bounds__(320) void k_y(const float* __restrict__ feat,
                                           const float* __restrict__ WreT,
                                           float* __restrict__ y) {
    __shared__ float fs[2][32];
    int t = threadIdx.x;
    int n0 = blockIdx.x * 2;
    if (t < 64) {
        int l = t >> 5, i = t & 31;
        fs[l][i] = feat[(long)(n0 + l) * 32 + i];
    }
    __syncthreads();
    int l = t / 160;
    int c = t - l * 160;
    float acc = 0.f;
#pragma unroll 8
    for (int i = 0; i < 32; ++i) acc += fs[l][i] * WreT[i * 160 + c];
    y[(long)(n0 + l) * 160 + c] = acc;
}

// Edge pass: msg[e,o] = y_b[src,o] + sum_f ea[e,f]*y_f[src,o]; scatter-add to aggr[dst]
__global__ void k_edge(const float* __restrict__ y, const float* __restrict__ ea,
                       const int* __restrict__ ei, float* __restrict__ aggr) {
    int idx = blockIdx.x * blockDim.x + threadIdx.x;
    if (idx >= EE * 32) return;
    int e = idx >> 5, o = idx & 31;
    int s = ei[e];
    int d = ei[EE + e];
    const float* yr = y + (long)s * 160;
    float a0 = ea[e * 4 + 0], a1 = ea[e * 4 + 1], a2 = ea[e * 4 + 2], a3 = ea[e * 4 + 3];
    float msg = yr[128 + o] + a0 * yr[o] + a1 * yr[32 + o] + a2 * yr[64 + o] + a3 * yr[96 + o];
    atomicAdd(aggr + (long)d * 32 + o, msg);
}

// Node update: m = relu(aggr + feat@root_w + conv_b); feat = GRU(m, feat)
// Thread = (node, output): 8 nodes x 32 outputs per block, 6250 blocks.
// f/m rows staged in LDS (broadcast); weights read as per-lane coalesced
// vector loads from transposed tables (L1-resident, 28KB total).
__global__ __launch_bounds__(256) void k_update(
    const float* __restrict__ aggr, const float* __restrict__ rootw,
    const float* __restrict__ convb, const float* __restrict__ wiT,
    const float* __restrict__ whT, const float* __restrict__ bi,
    const float* __restrict__ bh, float* __restrict__ feat) {
    __shared__ float fs[8][32];
    __shared__ float ms[8][32];
    int t = threadIdx.x;
    int l = t >> 5, o = t & 31;
    long n = (long)blockIdx.x * 8 + l;   // 50000 = 6250*8, no guard needed
    float f = feat[n * 32 + o];
    fs[l][o] = f;
    float m = aggr[n * 32 + o] + convb[o];
    __syncthreads();
#pragma unroll 8
    for (int i = 0; i < 32; ++i) m += fs[l][i] * rootw[i * 32 + o];
    m = fmaxf(m, 0.f);
    ms[l][o] = m;
    __syncthreads();
    float gir = bi[o], giz = bi[32 + o], gin = bi[64 + o];
    float ghr = bh[o], ghz = bh[32 + o], ghn = bh[64 + o];
#pragma unroll 8
    for (int k = 0; k < 32; ++k) {
        float mk = ms[l][k], hk = fs[l][k];
        const float* wik = wiT + k * 96 + o;
        const float* whk = whT + k * 96 + o;
        gir += mk * wik[0];
        giz += mk * wik[32];
        gin += mk * wik[64];
        ghr += hk * whk[0];
        ghz += hk * whk[32];
        ghn += hk * whk[64];
    }
    float r = 1.f / (1.f + __expf(-(gir + ghr)));
    float z = 1.f / (1.f + __expf(-(giz + ghz)));
    float nt = tanhf(gin + r * ghn);
    feat[n * 32 + o] = (1.f - z) * nt + z * f;
}

// Mean-pool per graph via atomics
__global__ void k_pool(const float* __restrict__ feat, const int* __restrict__ batch,
                       float* __restrict__ pooled, float* __restrict__ cnt) {
    int idx = blockIdx.x * blockDim.x + threadIdx.x;
    if (idx >= NN * 32) return;
    int n = idx >> 5, o = idx & 31;
    int g = batch[n];
    atomicAdd(pooled + (long)g * 32 + o, feat[idx]);
    if (o == 0) atomicAdd(cnt + g, 1.f);
}

// logits = (pooled/cnt) @ lin1_w.T + lin1_b; log_softmax over 2 classes
__global__ void k_final(const float* __restrict__ pooled, const float* __restrict__ cnt,
                        const float* __restrict__ w, const float* __restrict__ b,
                        float* __restrict__ out) {
    int g = blockIdx.x * blockDim.x + threadIdx.x;
    if (g >= GG) return;
    float inv = 1.f / fmaxf(cnt[g], 1.f);
    float l0 = b[0], l1 = b[1];
    const float* pr = pooled + g * 32;
#pragma unroll
    for (int k = 0; k < 32; ++k) {
        float p = pr[k] * inv;
        l0 += p * w[k];
        l1 += p * w[32 + k];
    }
    float mx = fmaxf(l0, l1);
    float lse = mx + logf(__expf(l0 - mx) + __expf(l1 - mx));
    out[g * 2 + 0] = l0 - lse;
    out[g * 2 + 1] = l1 - lse;
}

extern "C" void kernel_launch(void* const* d_in, const int* in_sizes, int n_in,
                              void* d_out, int out_size, void* d_ws, size_t ws_size,
                              hipStream_t stream) {
    const float* x        = (const float*)d_in[0];
    const float* edge_attr= (const float*)d_in[1];
    const float* lin0_w   = (const float*)d_in[2];
    const float* lin0_b   = (const float*)d_in[3];
    const float* nn_w     = (const float*)d_in[4];
    const float* nn_b     = (const float*)d_in[5];
    const float* root_w   = (const float*)d_in[6];
    const float* conv_b   = (const float*)d_in[7];
    const float* gru_wi   = (const float*)d_in[8];
    const float* gru_wh   = (const float*)d_in[9];
    const float* gru_bi   = (const float*)d_in[10];
    const float* gru_bh   = (const float*)d_in[11];
    const float* lin1_w   = (const float*)d_in[12];
    const float* lin1_b   = (const float*)d_in[13];
    const int*   edge_idx = (const int*)d_in[14];
    const int*   batch    = (const int*)d_in[15];
    float* out = (float*)d_out;

    float* ws     = (float*)d_ws;
    float* feat   = ws;                       // N*32   = 1,600,000 f
    float* y      = feat + (long)NN * 32;     // N*160  = 8,000,000 f
    float* aggr   = y + (long)NN * 160;       // N*32   = 1,600,000 f
    float* pooled = aggr + (long)NN * 32;     // G*32   =    65,536 f
    float* cnt    = pooled + (long)GG * 32;   // G      =     2,048 f
    float* Wre    = cnt + GG;                 // 160*32 =     5,120 f
    float* WreT   = Wre + 5120;               // 32*160 =     5,120 f
    float* wiT    = WreT + 5120;              // 32*96  =     3,072 f
    float* whT    = wiT + 3072;               // 32*96  =     3,072 f
    // total ~45.1 MB

    hipMemsetAsync(pooled, 0, ((long)GG * 32 + GG) * sizeof(float), stream);

    k_prep<<<64, 256, 0, stream>>>(nn_w, nn_b, gru_wi, gru_wh, Wre, WreT, wiT, whT);
    k_init<<<(NN * 32 + 255) / 256, 256, 0, stream>>>(x, lin0_w, lin0_b, feat);

    for (int it = 0; it < 3; ++it) {
        k_y<<<NN / 2, 320, 0, stream>>>(feat, WreT, y);
        hipMemsetAsync(aggr, 0, (long)NN * 32 * sizeof(float), stream);
        k_edge<<<(EE * 32 + 255) / 256, 256, 0, stream>>>(y, edge_attr, edge_idx, aggr);
        k_update<<<NN / 8, 256, 0, stream>>>(aggr, root_w, conv_b, wiT, whT,
                                             gru_bi, gru_bh, feat);
    }

    k_pool<<<(NN * 32 + 255) / 256, 256, 0, stream>>>(feat, batch, pooled, cnt);
    k_final<<<(GG + 255) / 256, 256, 0, stream>>>(pooled, cnt, lin1_w, lin1_b, out);
}

// Round 6
// 390.555 us; speedup vs baseline: 1.1345x; 1.1345x over previous
//
#include <hip/hip_runtime.h>
#include <hip/hip_bf16.h>

// Problem constants (from reference)
#define NN 50000
#define EE 100000
#define GG 2048
#define NB_SCAN 196   // ceil(NN/256)

// feat = relu(x @ lin0_w.T + lin0_b); thread per (node, out-dim)
__global__ void k_init(const float* __restrict__ x, const float* __restrict__ w,
                       const float* __restrict__ b, float* __restrict__ feat) {
    int idx = blockIdx.x * blockDim.x + threadIdx.x;
    if (idx >= NN * 32) return;
    int n = idx >> 5, o = idx & 31;
    const float* xr = x + n * 11;
    const float* wr = w + o * 11;
    float acc = b[o];
#pragma unroll
    for (int i = 0; i < 11; ++i) acc += xr[i] * wr[i];
    feat[idx] = fmaxf(acc, 0.f);
}

// Weight tables: Wre[c][i] (160x32) for k_y (wave-uniform s_load);
// wiT/whT[k][gate*32+o] (32x96) for the GRU (coalesced per-lane).
__global__ void k_prep(const float* __restrict__ nnw, const float* __restrict__ nnb,
                       const float* __restrict__ wi, const float* __restrict__ wh,
                       float* __restrict__ Wre, float* __restrict__ wiT,
                       float* __restrict__ whT) {
    int idx = blockIdx.x * blockDim.x + threadIdx.x;
    if (idx < 5120) {
        int c = idx >> 5, i = idx & 31;
        float v;
        if (c < 128) v = nnw[((i << 5) + (c & 31)) * 4 + (c >> 5)];
        else         v = nnb[(i << 5) + (c - 128)];
        Wre[idx] = v;
    } else if (idx < 8192) {
        int j = idx - 5120;
        int k = j / 96, c = j - k * 96;
        wiT[j] = wi[c * 32 + k];
    } else if (idx < 11264) {
        int j = idx - 8192;
        int k = j / 96, c = j - k * 96;
        whT[j] = wh[c * 32 + k];
    }
}

// ---- CSR build (once per launch; edges are iteration-invariant) ----
__global__ void k_hist(const int* __restrict__ ei, int* __restrict__ cnt) {
    int e = blockIdx.x * blockDim.x + threadIdx.x;
    if (e >= EE) return;
    atomicAdd(&cnt[ei[EE + e]], 1);
}

// per-block inclusive scan of cnt -> tmp; block sums -> bsum
__global__ __launch_bounds__(256) void k_scan1(const int* __restrict__ cnt,
                                               int* __restrict__ tmp,
                                               int* __restrict__ bsum) {
    __shared__ int sd[256];
    int t = threadIdx.x;
    int i = blockIdx.x * 256 + t;
    int v = (i < NN) ? cnt[i] : 0;
    sd[t] = v;
    __syncthreads();
#pragma unroll
    for (int off = 1; off < 256; off <<= 1) {
        int x = (t >= off) ? sd[t - off] : 0;
        __syncthreads();
        sd[t] += x;
        __syncthreads();
    }
    if (i < NN) tmp[i] = sd[t];
    if (t == 255) bsum[blockIdx.x] = sd[255];
}

// single block: inclusive scan of the NB_SCAN block sums
__global__ __launch_bounds__(256) void k_scan2(int* __restrict__ bsum) {
    __shared__ int sd[256];
    int t = threadIdx.x;
    int v = (t < NB_SCAN) ? bsum[t] : 0;
    sd[t] = v;
    __syncthreads();
#pragma unroll
    for (int off = 1; off < 256; off <<= 1) {
        int x = (t >= off) ? sd[t - off] : 0;
        __syncthreads();
        sd[t] += x;
        __syncthreads();
    }
    if (t < NB_SCAN) bsum[t] = sd[t];
}

// exclusive row_ptr = base + inclusive - own; cursor copy; row_ptr[NN]=EE
__global__ void k_scan3(const int* __restrict__ cnt, const int* __restrict__ tmp,
                        const int* __restrict__ bsum, int* __restrict__ row_ptr,
                        int* __restrict__ cursor) {
    int i = blockIdx.x * blockDim.x + threadIdx.x;
    if (i >= NN) return;
    int base = (blockIdx.x > 0) ? bsum[blockIdx.x - 1] : 0;
    int excl = base + tmp[i] - cnt[i];
    row_ptr[i] = excl;
    cursor[i] = excl;
    if (i == 0) row_ptr[NN] = EE;
}

// place each edge into its dst's CSR segment; pack src + edge_attr
__global__ void k_scatter(const int* __restrict__ ei, const float* __restrict__ ea,
                          int* __restrict__ cursor, int* __restrict__ esrc,
                          float4* __restrict__ eea) {
    int e = blockIdx.x * blockDim.x + threadIdx.x;
    if (e >= EE) return;
    int d = ei[EE + e];
    int slot = atomicAdd(&cursor[d], 1);
    esrc[slot] = ei[e];
    eea[slot] = make_float4(ea[e * 4 + 0], ea[e * 4 + 1], ea[e * 4 + 2], ea[e * 4 + 3]);
}

// y[n,c] = sum_i feat[n,i] * Wre[c*32+i]; lane = node, wave-uniform weights
// (s_load), wave computes a 10-col slice. Grid (782,4) x 4 waves.
__global__ __launch_bounds__(256) void k_y(const float* __restrict__ feat,
                                           const float* __restrict__ Wre,
                                           float* __restrict__ y) {
    int lane = threadIdx.x & 63;
    int wv = __builtin_amdgcn_readfirstlane(threadIdx.x >> 6);
    int n = blockIdx.x * 64 + lane;
    if (n >= NN) return;
    int c0 = blockIdx.y * 40 + wv * 10;
    float fr[32];
    const float4* f4 = (const float4*)(feat + (long)n * 32);
#pragma unroll
    for (int q = 0; q < 8; ++q) {
        float4 v = f4[q];
        fr[4 * q + 0] = v.x; fr[4 * q + 1] = v.y;
        fr[4 * q + 2] = v.z; fr[4 * q + 3] = v.w;
    }
    float acc[10];
#pragma unroll
    for (int cc = 0; cc < 10; ++cc) {
        const float* w = Wre + (c0 + cc) * 32;   // uniform address -> s_load
        float a = 0.f;
#pragma unroll
        for (int i = 0; i < 32; ++i) a += fr[i] * w[i];
        acc[cc] = a;
    }
    float* yr = y + (long)n * 160 + c0;          // c0 multiple of 10 -> 8B aligned
#pragma unroll
    for (int q = 0; q < 5; ++q)
        ((float2*)yr)[q] = make_float2(acc[2 * q], acc[2 * q + 1]);
}

// Fused: aggr gather (CSR, no atomics) + root matvec + GRU.
// Thread = (node, o): 8 nodes x 32 per block.
__global__ __launch_bounds__(256) void k_conv_update(
    const float* __restrict__ y, const int* __restrict__ row_ptr,
    const int* __restrict__ esrc, const float4* __restrict__ eea,
    const float* __restrict__ rootw, const float* __restrict__ convb,
    const float* __restrict__ wiT, const float* __restrict__ whT,
    const float* __restrict__ bi, const float* __restrict__ bh,
    float* __restrict__ feat) {
    __shared__ float fs[8][32];
    __shared__ float ms[8][32];
    int t = threadIdx.x;
    int l = t >> 5, o = t & 31;
    long n = (long)blockIdx.x * 8 + l;   // 50000 = 6250*8
    float f = feat[n * 32 + o];
    fs[l][o] = f;
    float m = convb[o];
    int e0 = row_ptr[n], e1 = row_ptr[n + 1];
    for (int e = e0; e < e1; ++e) {
        int s = esrc[e];                 // uniform across the 32-lane group
        float4 a = eea[e];
        const float* yr = y + (long)s * 160;
        m += yr[128 + o] + a.x * yr[o] + a.y * yr[32 + o]
                         + a.z * yr[64 + o] + a.w * yr[96 + o];
    }
    __syncthreads();
#pragma unroll 8
    for (int i = 0; i < 32; ++i) m += fs[l][i] * rootw[i * 32 + o];
    m = fmaxf(m, 0.f);
    ms[l][o] = m;
    __syncthreads();
    float gir = bi[o], giz = bi[32 + o], gin = bi[64 + o];
    float ghr = bh[o], ghz = bh[32 + o], ghn = bh[64 + o];
#pragma unroll 8
    for (int k = 0; k < 32; ++k) {
        float mk = ms[l][k], hk = fs[l][k];
        const float* wik = wiT + k * 96 + o;
        const float* whk = whT + k * 96 + o;
        gir += mk * wik[0];
        giz += mk * wik[32];
        gin += mk * wik[64];
        ghr += hk * whk[0];
        ghz += hk * whk[32];
        ghn += hk * whk[64];
    }
    float r = 1.f / (1.f + __expf(-(gir + ghr)));
    float z = 1.f / (1.f + __expf(-(giz + ghz)));
    float nt = tanhf(gin + r * ghn);
    feat[n * 32 + o] = (1.f - z) * nt + z * f;
}

// Mean-pool per graph via atomics
__global__ void k_pool(const float* __restrict__ feat, const int* __restrict__ batch,
                       float* __restrict__ pooled, float* __restrict__ cnt) {
    int idx = blockIdx.x * blockDim.x + threadIdx.x;
    if (idx >= NN * 32) return;
    int n = idx >> 5, o = idx & 31;
    int g = batch[n];
    atomicAdd(pooled + (long)g * 32 + o, feat[idx]);
    if (o == 0) atomicAdd(cnt + g, 1.f);
}

// logits = (pooled/cnt) @ lin1_w.T + lin1_b; log_softmax over 2 classes
__global__ void k_final(const float* __restrict__ pooled, const float* __restrict__ cnt,
                        const float* __restrict__ w, const float* __restrict__ b,
                        float* __restrict__ out) {
    int g = blockIdx.x * blockDim.x + threadIdx.x;
    if (g >= GG) return;
    float inv = 1.f / fmaxf(cnt[g], 1.f);
    float l0 = b[0], l1 = b[1];
    const float* pr = pooled + g * 32;
#pragma unroll
    for (int k = 0; k < 32; ++k) {
        float p = pr[k] * inv;
        l0 += p * w[k];
        l1 += p * w[32 + k];
    }
    float mx = fmaxf(l0, l1);
    float lse = mx + logf(__expf(l0 - mx) + __expf(l1 - mx));
    out[g * 2 + 0] = l0 - lse;
    out[g * 2 + 1] = l1 - lse;
}

extern "C" void kernel_launch(void* const* d_in, const int* in_sizes, int n_in,
                              void* d_out, int out_size, void* d_ws, size_t ws_size,
                              hipStream_t stream) {
    const float* x        = (const float*)d_in[0];
    const float* edge_attr= (const float*)d_in[1];
    const float* lin0_w   = (const float*)d_in[2];
    const float* lin0_b   = (const float*)d_in[3];
    const float* nn_w     = (const float*)d_in[4];
    const float* nn_b     = (const float*)d_in[5];
    const float* root_w   = (const float*)d_in[6];
    const float* conv_b   = (const float*)d_in[7];
    const float* gru_wi   = (const float*)d_in[8];
    const float* gru_wh   = (const float*)d_in[9];
    const float* gru_bi   = (const float*)d_in[10];
    const float* gru_bh   = (const float*)d_in[11];
    const float* lin1_w   = (const float*)d_in[12];
    const float* lin1_b   = (const float*)d_in[13];
    const int*   edge_idx = (const int*)d_in[14];
    const int*   batch    = (const int*)d_in[15];
    float* out = (float*)d_out;

    float* ws     = (float*)d_ws;
    float* feat   = ws;                        // N*32   = 1,600,000 f
    float* y      = feat + (long)NN * 32;      // N*160  = 8,000,000 f
    float* pooled = y + (long)NN * 160;        // G*32
    float* cnt    = pooled + (long)GG * 32;    // G
    float* Wre    = cnt + GG;                  // 5120 f
    float* wiT    = Wre + 5120;                // 3072 f
    float* whT    = wiT + 3072;                // 3072 f
    int*   row_cnt= (int*)(whT + 3072);        // 50000 i
    int*   tmp    = row_cnt + NN;              // 50000 i
    int*   bsum   = tmp + NN;                  // 256 i
    int*   row_ptr= bsum + 256;                // 50001 i
    int*   cursor = row_ptr + NN + 1;          // 50000 i
    int*   esrc   = cursor + NN;               // 100000 i
    size_t off = ((size_t)((char*)(esrc + EE) - (char*)d_ws) + 15) & ~(size_t)15;
    float4* eea  = (float4*)((char*)d_ws + off); // 100000 float4
    // total ~= 43 MB

    hipMemsetAsync(pooled, 0, ((long)GG * 32 + GG) * sizeof(float), stream);
    hipMemsetAsync(row_cnt, 0, NN * sizeof(int), stream);

    k_prep<<<44, 256, 0, stream>>>(nn_w, nn_b, gru_wi, gru_wh, Wre, wiT, whT);
    k_init<<<(NN * 32 + 255) / 256, 256, 0, stream>>>(x, lin0_w, lin0_b, feat);

    // CSR build (iteration-invariant)
    k_hist<<<(EE + 255) / 256, 256, 0, stream>>>(edge_idx, row_cnt);
    k_scan1<<<NB_SCAN, 256, 0, stream>>>(row_cnt, tmp, bsum);
    k_scan2<<<1, 256, 0, stream>>>(bsum);
    k_scan3<<<NB_SCAN, 256, 0, stream>>>(row_cnt, tmp, bsum, row_ptr, cursor);
    k_scatter<<<(EE + 255) / 256, 256, 0, stream>>>(edge_idx, edge_attr, cursor, esrc, eea);

    dim3 gy((NN + 63) / 64, 4);
    for (int it = 0; it < 3; ++it) {
        k_y<<<gy, 256, 0, stream>>>(feat, Wre, y);
        k_conv_update<<<NN / 8, 256, 0, stream>>>(y, row_ptr, esrc, eea, root_w, conv_b,
                                                  wiT, whT, gru_bi, gru_bh, feat);
    }

    k_pool<<<(NN * 32 + 255) / 256, 256, 0, stream>>>(feat, batch, pooled, cnt);
    k_final<<<(GG + 255) / 256, 256, 0, stream>>>(pooled, cnt, lin1_w, lin1_b, out);
}

// Round 7
// 343.715 us; speedup vs baseline: 1.2891x; 1.1363x over previous
//
#include <hip/hip_runtime.h>
#include <hip/hip_bf16.h>

// Problem constants (from reference)
#define NN 50000
#define EE 100000
#define GG 2048
#define NB_SCAN 196   // ceil(NN/256)

// feat = relu(x @ lin0_w.T + lin0_b); thread per (node, out-dim)
__global__ void k_init(const float* __restrict__ x, const float* __restrict__ w,
                       const float* __restrict__ b, float* __restrict__ feat) {
    int idx = blockIdx.x * blockDim.x + threadIdx.x;
    if (idx >= NN * 32) return;
    int n = idx >> 5, o = idx & 31;
    const float* xr = x + n * 11;
    const float* wr = w + o * 11;
    float acc = b[o];
#pragma unroll
    for (int i = 0; i < 11; ++i) acc += xr[i] * wr[i];
    feat[idx] = fmaxf(acc, 0.f);
}

// Weight tables: Wre[c][i] (160x32) for k_y (wave-uniform s_load);
// wiT/whT[k][gate*32+o] (32x96) for the GRU (coalesced per-lane).
__global__ void k_prep(const float* __restrict__ nnw, const float* __restrict__ nnb,
                       const float* __restrict__ wi, const float* __restrict__ wh,
                       float* __restrict__ Wre, float* __restrict__ wiT,
                       float* __restrict__ whT) {
    int idx = blockIdx.x * blockDim.x + threadIdx.x;
    if (idx < 5120) {
        int c = idx >> 5, i = idx & 31;
        float v;
        if (c < 128) v = nnw[((i << 5) + (c & 31)) * 4 + (c >> 5)];
        else         v = nnb[(i << 5) + (c - 128)];
        Wre[idx] = v;
    } else if (idx < 8192) {
        int j = idx - 5120;
        int k = j / 96, c = j - k * 96;
        wiT[j] = wi[c * 32 + k];
    } else if (idx < 11264) {
        int j = idx - 8192;
        int k = j / 96, c = j - k * 96;
        whT[j] = wh[c * 32 + k];
    }
}

// ---- CSR build (once per launch; edges are iteration-invariant) ----
__global__ void k_hist(const int* __restrict__ ei, int* __restrict__ cnt) {
    int e = blockIdx.x * blockDim.x + threadIdx.x;
    if (e >= EE) return;
    atomicAdd(&cnt[ei[EE + e]], 1);
}

// per-block inclusive scan of cnt -> tmp; block sums -> bsum
__global__ __launch_bounds__(256) void k_scan1(const int* __restrict__ cnt,
                                               int* __restrict__ tmp,
                                               int* __restrict__ bsum) {
    __shared__ int sd[256];
    int t = threadIdx.x;
    int i = blockIdx.x * 256 + t;
    int v = (i < NN) ? cnt[i] : 0;
    sd[t] = v;
    __syncthreads();
#pragma unroll
    for (int off = 1; off < 256; off <<= 1) {
        int x = (t >= off) ? sd[t - off] : 0;
        __syncthreads();
        sd[t] += x;
        __syncthreads();
    }
    if (i < NN) tmp[i] = sd[t];
    if (t == 255) bsum[blockIdx.x] = sd[255];
}

// single block: inclusive scan of the NB_SCAN block sums
__global__ __launch_bounds__(256) void k_scan2(int* __restrict__ bsum) {
    __shared__ int sd[256];
    int t = threadIdx.x;
    int v = (t < NB_SCAN) ? bsum[t] : 0;
    sd[t] = v;
    __syncthreads();
#pragma unroll
    for (int off = 1; off < 256; off <<= 1) {
        int x = (t >= off) ? sd[t - off] : 0;
        __syncthreads();
        sd[t] += x;
        __syncthreads();
    }
    if (t < NB_SCAN) bsum[t] = sd[t];
}

// exclusive row_ptr = base + inclusive - own; cursor copy; row_ptr[NN]=EE
__global__ void k_scan3(const int* __restrict__ cnt, const int* __restrict__ tmp,
                        const int* __restrict__ bsum, int* __restrict__ row_ptr,
                        int* __restrict__ cursor) {
    int i = blockIdx.x * blockDim.x + threadIdx.x;
    if (i >= NN) return;
    int base = (blockIdx.x > 0) ? bsum[blockIdx.x - 1] : 0;
    int excl = base + tmp[i] - cnt[i];
    row_ptr[i] = excl;
    cursor[i] = excl;
    if (i == 0) row_ptr[NN] = EE;
}

// place each edge into its dst's CSR segment; pack src + edge_attr
__global__ void k_scatter(const int* __restrict__ ei, const float* __restrict__ ea,
                          int* __restrict__ cursor, int* __restrict__ esrc,
                          float4* __restrict__ eea) {
    int e = blockIdx.x * blockDim.x + threadIdx.x;
    if (e >= EE) return;
    int d = ei[EE + e];
    int slot = atomicAdd(&cursor[d], 1);
    esrc[slot] = ei[e];
    eea[slot] = make_float4(ea[e * 4 + 0], ea[e * 4 + 1], ea[e * 4 + 2], ea[e * 4 + 3]);
}

// y[n,c] = sum_i feat[n,i] * Wre[c*32+i]; lane = node, wave-uniform weights
// (s_load), wave computes a 10-col slice. Grid (782,4) x 4 waves.
__global__ __launch_bounds__(256) void k_y(const float* __restrict__ feat,
                                           const float* __restrict__ Wre,
                                           float* __restrict__ y) {
    int lane = threadIdx.x & 63;
    int wv = __builtin_amdgcn_readfirstlane(threadIdx.x >> 6);
    int n = blockIdx.x * 64 + lane;
    if (n >= NN) return;
    int c0 = blockIdx.y * 40 + wv * 10;
    float fr[32];
    const float4* f4 = (const float4*)(feat + (long)n * 32);
#pragma unroll
    for (int q = 0; q < 8; ++q) {
        float4 v = f4[q];
        fr[4 * q + 0] = v.x; fr[4 * q + 1] = v.y;
        fr[4 * q + 2] = v.z; fr[4 * q + 3] = v.w;
    }
    float acc[10];
#pragma unroll
    for (int cc = 0; cc < 10; ++cc) {
        const float* w = Wre + (c0 + cc) * 32;   // uniform address -> s_load
        float a = 0.f;
#pragma unroll
        for (int i = 0; i < 32; ++i) a += fr[i] * w[i];
        acc[cc] = a;
    }
    float* yr = y + (long)n * 160 + c0;          // c0 multiple of 10 -> 8B aligned
#pragma unroll
    for (int q = 0; q < 5; ++q)
        ((float2*)yr)[q] = make_float2(acc[2 * q], acc[2 * q + 1]);
}

// Fused: aggr gather (CSR, no atomics) + root matvec + GRU.
// 32-lane group = 4 nodes (register-blocked); block = 8 groups = 32 nodes.
// Each weight load feeds 4 FMAs (1:4 load:FMA) and 4 independent acc chains.
__global__ __launch_bounds__(256) void k_conv_update(
    const float* __restrict__ y, const int* __restrict__ row_ptr,
    const int* __restrict__ esrc, const float4* __restrict__ eea,
    const float* __restrict__ rootw, const float* __restrict__ convb,
    const float* __restrict__ wiT, const float* __restrict__ whT,
    const float* __restrict__ bi, const float* __restrict__ bh,
    float* __restrict__ feat) {
    __shared__ float fs[32][32];
    __shared__ float ms[32][32];
    int t = threadIdx.x;
    int g = t >> 5, o = t & 31;
    int nb = blockIdx.x * 32 + g * 4;    // first node of this 32-lane group
    float f[4], m[4];
#pragma unroll
    for (int j = 0; j < 4; ++j) {
        int n = nb + j;
        bool v = (n < NN);
        f[j] = v ? feat[(long)n * 32 + o] : 0.f;
        fs[g * 4 + j][o] = f[j];
        m[j] = convb[o];
        if (v) {
            int e0 = row_ptr[n], e1 = row_ptr[n + 1];
            for (int e = e0; e < e1; ++e) {
                int s = esrc[e];         // uniform across the 32-lane group
                float4 a = eea[e];
                const float* yr = y + (long)s * 160;
                m[j] += yr[128 + o] + a.x * yr[o] + a.y * yr[32 + o]
                                    + a.z * yr[64 + o] + a.w * yr[96 + o];
            }
        }
    }
    __syncthreads();
    // root matvec: m[j] += sum_i fs[..][i] * rootw[i*32+o]; 1 load : 4 FMA
#pragma unroll 4
    for (int i = 0; i < 32; ++i) {
        float rw = rootw[i * 32 + o];
#pragma unroll
        for (int j = 0; j < 4; ++j) m[j] += fs[g * 4 + j][i] * rw;
    }
#pragma unroll
    for (int j = 0; j < 4; ++j) {
        m[j] = fmaxf(m[j], 0.f);
        ms[g * 4 + j][o] = m[j];
    }
    __syncthreads();
    float bir = bi[o], biz = bi[32 + o], bin_ = bi[64 + o];
    float bhr = bh[o], bhz = bh[32 + o], bhn = bh[64 + o];
    float gir[4], giz[4], gin_[4], ghr[4], ghz[4], ghn[4];
#pragma unroll
    for (int j = 0; j < 4; ++j) {
        gir[j] = bir; giz[j] = biz; gin_[j] = bin_;
        ghr[j] = bhr; ghz[j] = bhz; ghn[j] = bhn;
    }
#pragma unroll 2
    for (int k = 0; k < 32; ++k) {
        const float* wik = wiT + k * 96 + o;
        const float* whk = whT + k * 96 + o;
        float wir = wik[0], wiz = wik[32], win = wik[64];
        float whr = whk[0], whz = whk[32], whn = whk[64];
#pragma unroll
        for (int j = 0; j < 4; ++j) {
            float mk = ms[g * 4 + j][k], hk = fs[g * 4 + j][k];
            gir[j] += mk * wir;
            giz[j] += mk * wiz;
            gin_[j] += mk * win;
            ghr[j] += hk * whr;
            ghz[j] += hk * whz;
            ghn[j] += hk * whn;
        }
    }
#pragma unroll
    for (int j = 0; j < 4; ++j) {
        int n = nb + j;
        if (n < NN) {
            float r = 1.f / (1.f + __expf(-(gir[j] + ghr[j])));
            float z = 1.f / (1.f + __expf(-(giz[j] + ghz[j])));
            float nt = tanhf(gin_[j] + r * ghn[j]);
            feat[(long)n * 32 + o] = (1.f - z) * nt + z * f[j];
        }
    }
}

// Mean-pool per graph via atomics
__global__ void k_pool(const float* __restrict__ feat, const int* __restrict__ batch,
                       float* __restrict__ pooled, float* __restrict__ cnt) {
    int idx = blockIdx.x * blockDim.x + threadIdx.x;
    if (idx >= NN * 32) return;
    int n = idx >> 5, o = idx & 31;
    int g = batch[n];
    atomicAdd(pooled + (long)g * 32 + o, feat[idx]);
    if (o == 0) atomicAdd(cnt + g, 1.f);
}

// logits = (pooled/cnt) @ lin1_w.T + lin1_b; log_softmax over 2 classes
__global__ void k_final(const float* __restrict__ pooled, const float* __restrict__ cnt,
                        const float* __restrict__ w, const float* __restrict__ b,
                        float* __restrict__ out) {
    int g = blockIdx.x * blockDim.x + threadIdx.x;
    if (g >= GG) return;
    float inv = 1.f / fmaxf(cnt[g], 1.f);
    float l0 = b[0], l1 = b[1];
    const float* pr = pooled + g * 32;
#pragma unroll
    for (int k = 0; k < 32; ++k) {
        float p = pr[k] * inv;
        l0 += p * w[k];
        l1 += p * w[32 + k];
    }
    float mx = fmaxf(l0, l1);
    float lse = mx + logf(__expf(l0 - mx) + __expf(l1 - mx));
    out[g * 2 + 0] = l0 - lse;
    out[g * 2 + 1] = l1 - lse;
}

extern "C" void kernel_launch(void* const* d_in, const int* in_sizes, int n_in,
                              void* d_out, int out_size, void* d_ws, size_t ws_size,
                              hipStream_t stream) {
    const float* x        = (const float*)d_in[0];
    const float* edge_attr= (const float*)d_in[1];
    const float* lin0_w   = (const float*)d_in[2];
    const float* lin0_b   = (const float*)d_in[3];
    const float* nn_w     = (const float*)d_in[4];
    const float* nn_b     = (const float*)d_in[5];
    const float* root_w   = (const float*)d_in[6];
    const float* conv_b   = (const float*)d_in[7];
    const float* gru_wi   = (const float*)d_in[8];
    const float* gru_wh   = (const float*)d_in[9];
    const float* gru_bi   = (const float*)d_in[10];
    const float* gru_bh   = (const float*)d_in[11];
    const float* lin1_w   = (const float*)d_in[12];
    const float* lin1_b   = (const float*)d_in[13];
    const int*   edge_idx = (const int*)d_in[14];
    const int*   batch    = (const int*)d_in[15];
    float* out = (float*)d_out;

    float* ws     = (float*)d_ws;
    float* feat   = ws;                        // N*32   = 1,600,000 f
    float* y      = feat + (long)NN * 32;      // N*160  = 8,000,000 f
    float* pooled = y + (long)NN * 160;        // G*32
    float* cnt    = pooled + (long)GG * 32;    // G
    float* Wre    = cnt + GG;                  // 5120 f
    float* wiT    = Wre + 5120;                // 3072 f
    float* whT    = wiT + 3072;                // 3072 f
    int*   row_cnt= (int*)(whT + 3072);        // 50000 i
    int*   tmp    = row_cnt + NN;              // 50000 i
    int*   bsum   = tmp + NN;                  // 256 i
    int*   row_ptr= bsum + 256;                // 50001 i
    int*   cursor = row_ptr + NN + 1;          // 50000 i
    int*   esrc   = cursor + NN;               // 100000 i
    size_t off = ((size_t)((char*)(esrc + EE) - (char*)d_ws) + 15) & ~(size_t)15;
    float4* eea  = (float4*)((char*)d_ws + off); // 100000 float4
    // total ~= 43 MB

    hipMemsetAsync(pooled, 0, ((long)GG * 32 + GG) * sizeof(float), stream);
    hipMemsetAsync(row_cnt, 0, NN * sizeof(int), stream);

    k_prep<<<44, 256, 0, stream>>>(nn_w, nn_b, gru_wi, gru_wh, Wre, wiT, whT);
    k_init<<<(NN * 32 + 255) / 256, 256, 0, stream>>>(x, lin0_w, lin0_b, feat);

    // CSR build (iteration-invariant)
    k_hist<<<(EE + 255) / 256, 256, 0, stream>>>(edge_idx, row_cnt);
    k_scan1<<<NB_SCAN, 256, 0, stream>>>(row_cnt, tmp, bsum);
    k_scan2<<<1, 256, 0, stream>>>(bsum);
    k_scan3<<<NB_SCAN, 256, 0, stream>>>(row_cnt, tmp, bsum, row_ptr, cursor);
    k_scatter<<<(EE + 255) / 256, 256, 0, stream>>>(edge_idx, edge_attr, cursor, esrc, eea);

    dim3 gy((NN + 63) / 64, 4);
    for (int it = 0; it < 3; ++it) {
        k_y<<<gy, 256, 0, stream>>>(feat, Wre, y);
        k_conv_update<<<(NN + 31) / 32, 256, 0, stream>>>(y, row_ptr, esrc, eea,
                                                          root_w, conv_b, wiT, whT,
                                                          gru_bi, gru_bh, feat);
    }

    k_pool<<<(NN * 32 + 255) / 256, 256, 0, stream>>>(feat, batch, pooled, cnt);
    k_final<<<(GG + 255) / 256, 256, 0, stream>>>(pooled, cnt, lin1_w, lin1_b, out);
}

// Round 8
// 336.316 us; speedup vs baseline: 1.3175x; 1.0220x over previous
//
#include <hip/hip_runtime.h>
#include <hip/hip_bf16.h>

// Problem constants (from reference)
#define NN 50000
#define EE 100000
#define GG 2048
#define NB_SCAN 196   // ceil(NN/256)

__device__ __forceinline__ float b2f(unsigned short u) {
    union { unsigned int i; float f; } x; x.i = (unsigned int)u << 16; return x.f;
}
__device__ __forceinline__ unsigned short f2b(float f) {
    union { float f; unsigned int i; } x; x.f = f;
    unsigned int b = x.i + (0x7FFFu + ((x.i >> 16) & 1u));   // RNE
    return (unsigned short)(b >> 16);
}

// feat = relu(x @ lin0_w.T + lin0_b); thread per (node, out-dim)
__global__ void k_init(const float* __restrict__ x, const float* __restrict__ w,
                       const float* __restrict__ b, float* __restrict__ feat) {
    int idx = blockIdx.x * blockDim.x + threadIdx.x;
    if (idx >= NN * 32) return;
    int n = idx >> 5, o = idx & 31;
    const float* xr = x + n * 11;
    const float* wr = w + o * 11;
    float acc = b[o];
#pragma unroll
    for (int i = 0; i < 11; ++i) acc += xr[i] * wr[i];
    feat[idx] = fmaxf(acc, 0.f);
}

// Weight tables: Wre[c][i] (160x32) for k_y (wave-uniform s_load);
// wiT/whT[k][gate*32+o] (32x96) for the GRU (coalesced per-lane).
__global__ void k_prep(const float* __restrict__ nnw, const float* __restrict__ nnb,
                       const float* __restrict__ wi, const float* __restrict__ wh,
                       float* __restrict__ Wre, float* __restrict__ wiT,
                       float* __restrict__ whT) {
    int idx = blockIdx.x * blockDim.x + threadIdx.x;
    if (idx < 5120) {
        int c = idx >> 5, i = idx & 31;
        float v;
        if (c < 128) v = nnw[((i << 5) + (c & 31)) * 4 + (c >> 5)];
        else         v = nnb[(i << 5) + (c - 128)];
        Wre[idx] = v;
    } else if (idx < 8192) {
        int j = idx - 5120;
        int k = j / 96, c = j - k * 96;
        wiT[j] = wi[c * 32 + k];
    } else if (idx < 11264) {
        int j = idx - 8192;
        int k = j / 96, c = j - k * 96;
        whT[j] = wh[c * 32 + k];
    }
}

// ---- CSR build (once per launch; edges are iteration-invariant) ----
__global__ void k_hist(const int* __restrict__ ei, int* __restrict__ cnt) {
    int e = blockIdx.x * blockDim.x + threadIdx.x;
    if (e >= EE) return;
    atomicAdd(&cnt[ei[EE + e]], 1);
}

__global__ __launch_bounds__(256) void k_scan1(const int* __restrict__ cnt,
                                               int* __restrict__ tmp,
                                               int* __restrict__ bsum) {
    __shared__ int sd[256];
    int t = threadIdx.x;
    int i = blockIdx.x * 256 + t;
    int v = (i < NN) ? cnt[i] : 0;
    sd[t] = v;
    __syncthreads();
#pragma unroll
    for (int off = 1; off < 256; off <<= 1) {
        int x = (t >= off) ? sd[t - off] : 0;
        __syncthreads();
        sd[t] += x;
        __syncthreads();
    }
    if (i < NN) tmp[i] = sd[t];
    if (t == 255) bsum[blockIdx.x] = sd[255];
}

__global__ __launch_bounds__(256) void k_scan2(int* __restrict__ bsum) {
    __shared__ int sd[256];
    int t = threadIdx.x;
    int v = (t < NB_SCAN) ? bsum[t] : 0;
    sd[t] = v;
    __syncthreads();
#pragma unroll
    for (int off = 1; off < 256; off <<= 1) {
        int x = (t >= off) ? sd[t - off] : 0;
        __syncthreads();
        sd[t] += x;
        __syncthreads();
    }
    if (t < NB_SCAN) bsum[t] = sd[t];
}

__global__ void k_scan3(const int* __restrict__ cnt, const int* __restrict__ tmp,
                        const int* __restrict__ bsum, int* __restrict__ row_ptr,
                        int* __restrict__ cursor) {
    int i = blockIdx.x * blockDim.x + threadIdx.x;
    if (i >= NN) return;
    int base = (blockIdx.x > 0) ? bsum[blockIdx.x - 1] : 0;
    int excl = base + tmp[i] - cnt[i];
    row_ptr[i] = excl;
    cursor[i] = excl;
    if (i == 0) row_ptr[NN] = EE;
}

__global__ void k_scatter(const int* __restrict__ ei, const float* __restrict__ ea,
                          int* __restrict__ cursor, int* __restrict__ esrc,
                          float4* __restrict__ eea) {
    int e = blockIdx.x * blockDim.x + threadIdx.x;
    if (e >= EE) return;
    int d = ei[EE + e];
    int slot = atomicAdd(&cursor[d], 1);
    esrc[slot] = ei[e];
    eea[slot] = make_float4(ea[e * 4 + 0], ea[e * 4 + 1], ea[e * 4 + 2], ea[e * 4 + 3]);
}

// y[n,c] = sum_i feat[n,i] * Wre[c*32+i]; lane = node, wave-uniform weights
// (s_load), wave computes a 10-col slice; output stored as bf16.
__global__ __launch_bounds__(256) void k_y(const float* __restrict__ feat,
                                           const float* __restrict__ Wre,
                                           unsigned short* __restrict__ yb) {
    int lane = threadIdx.x & 63;
    int wv = __builtin_amdgcn_readfirstlane(threadIdx.x >> 6);
    int n = blockIdx.x * 64 + lane;
    if (n >= NN) return;
    int c0 = blockIdx.y * 40 + wv * 10;
    float fr[32];
    const float4* f4 = (const float4*)(feat + (long)n * 32);
#pragma unroll
    for (int q = 0; q < 8; ++q) {
        float4 v = f4[q];
        fr[4 * q + 0] = v.x; fr[4 * q + 1] = v.y;
        fr[4 * q + 2] = v.z; fr[4 * q + 3] = v.w;
    }
    float acc[10];
#pragma unroll
    for (int cc = 0; cc < 10; ++cc) {
        const float* w = Wre + (c0 + cc) * 32;   // uniform address -> s_load
        float a = 0.f;
#pragma unroll
        for (int i = 0; i < 32; ++i) a += fr[i] * w[i];
        acc[cc] = a;
    }
    unsigned short* yr = yb + (long)n * 160 + c0;  // c0*2 bytes, 4B aligned
#pragma unroll
    for (int q = 0; q < 5; ++q) {
        unsigned int wlo = f2b(acc[2 * q]);
        unsigned int whi = f2b(acc[2 * q + 1]);
        ((unsigned int*)yr)[q] = wlo | (whi << 16);
    }
}

// Fused: aggr gather (CSR, no atomics, bf16 y) + root matvec + GRU.
// 32-lane group = 4 nodes (register-blocked); block = 8 groups = 32 nodes.
__global__ __launch_bounds__(256) void k_conv_update(
    const unsigned short* __restrict__ yb, const int* __restrict__ row_ptr,
    const int* __restrict__ esrc, const float4* __restrict__ eea,
    const float* __restrict__ rootw, const float* __restrict__ convb,
    const float* __restrict__ wiT, const float* __restrict__ whT,
    const float* __restrict__ bi, const float* __restrict__ bh,
    float* __restrict__ feat) {
    __shared__ float fs[32][32];
    __shared__ float ms[32][32];
    int t = threadIdx.x;
    int g = t >> 5, o = t & 31;
    int nb = blockIdx.x * 32 + g * 4;
    float f[4], m[4];
#pragma unroll
    for (int j = 0; j < 4; ++j) {
        int n = nb + j;
        bool v = (n < NN);
        f[j] = v ? feat[(long)n * 32 + o] : 0.f;
        fs[g * 4 + j][o] = f[j];
        m[j] = convb[o];
        if (v) {
            int e0 = row_ptr[n], e1 = row_ptr[n + 1];
            for (int e = e0; e < e1; ++e) {
                int s = esrc[e];         // uniform across the 32-lane group
                float4 a = eea[e];
                const unsigned short* yr = yb + (long)s * 160;
                float y0 = b2f(yr[o]);
                float y1 = b2f(yr[32 + o]);
                float y2 = b2f(yr[64 + o]);
                float y3 = b2f(yr[96 + o]);
                float y4 = b2f(yr[128 + o]);
                m[j] += y4 + a.x * y0 + a.y * y1 + a.z * y2 + a.w * y3;
            }
        }
    }
    __syncthreads();
#pragma unroll 4
    for (int i = 0; i < 32; ++i) {
        float rw = rootw[i * 32 + o];
#pragma unroll
        for (int j = 0; j < 4; ++j) m[j] += fs[g * 4 + j][i] * rw;
    }
#pragma unroll
    for (int j = 0; j < 4; ++j) {
        m[j] = fmaxf(m[j], 0.f);
        ms[g * 4 + j][o] = m[j];
    }
    __syncthreads();
    float bir = bi[o], biz = bi[32 + o], bin_ = bi[64 + o];
    float bhr = bh[o], bhz = bh[32 + o], bhn = bh[64 + o];
    float gir[4], giz[4], gin_[4], ghr[4], ghz[4], ghn[4];
#pragma unroll
    for (int j = 0; j < 4; ++j) {
        gir[j] = bir; giz[j] = biz; gin_[j] = bin_;
        ghr[j] = bhr; ghz[j] = bhz; ghn[j] = bhn;
    }
#pragma unroll 2
    for (int k = 0; k < 32; ++k) {
        const float* wik = wiT + k * 96 + o;
        const float* whk = whT + k * 96 + o;
        float wir = wik[0], wiz = wik[32], win = wik[64];
        float whr = whk[0], whz = whk[32], whn = whk[64];
#pragma unroll
        for (int j = 0; j < 4; ++j) {
            float mk = ms[g * 4 + j][k], hk = fs[g * 4 + j][k];
            gir[j] += mk * wir;
            giz[j] += mk * wiz;
            gin_[j] += mk * win;
            ghr[j] += hk * whr;
            ghz[j] += hk * whz;
            ghn[j] += hk * whn;
        }
    }
#pragma unroll
    for (int j = 0; j < 4; ++j) {
        int n = nb + j;
        if (n < NN) {
            float r = 1.f / (1.f + __expf(-(gir[j] + ghr[j])));
            float z = 1.f / (1.f + __expf(-(giz[j] + ghz[j])));
            float nt = tanhf(gin_[j] + r * ghn[j]);
            feat[(long)n * 32 + o] = (1.f - z) * nt + z * f[j];
        }
    }
}

// Mean-pool per graph via atomics
__global__ void k_pool(const float* __restrict__ feat, const int* __restrict__ batch,
                       float* __restrict__ pooled, float* __restrict__ cnt) {
    int idx = blockIdx.x * blockDim.x + threadIdx.x;
    if (idx >= NN * 32) return;
    int n = idx >> 5, o = idx & 31;
    int g = batch[n];
    atomicAdd(pooled + (long)g * 32 + o, feat[idx]);
    if (o == 0) atomicAdd(cnt + g, 1.f);
}

// logits = (pooled/cnt) @ lin1_w.T + lin1_b; log_softmax over 2 classes
__global__ void k_final(const float* __restrict__ pooled, const float* __restrict__ cnt,
                        const float* __restrict__ w, const float* __restrict__ b,
                        float* __restrict__ out) {
    int g = blockIdx.x * blockDim.x + threadIdx.x;
    if (g >= GG) return;
    float inv = 1.f / fmaxf(cnt[g], 1.f);
    float l0 = b[0], l1 = b[1];
    const float* pr = pooled + g * 32;
#pragma unroll
    for (int k = 0; k < 32; ++k) {
        float p = pr[k] * inv;
        l0 += p * w[k];
        l1 += p * w[32 + k];
    }
    float mx = fmaxf(l0, l1);
    float lse = mx + logf(__expf(l0 - mx) + __expf(l1 - mx));
    out[g * 2 + 0] = l0 - lse;
    out[g * 2 + 1] = l1 - lse;
}

extern "C" void kernel_launch(void* const* d_in, const int* in_sizes, int n_in,
                              void* d_out, int out_size, void* d_ws, size_t ws_size,
                              hipStream_t stream) {
    const float* x        = (const float*)d_in[0];
    const float* edge_attr= (const float*)d_in[1];
    const float* lin0_w   = (const float*)d_in[2];
    const float* lin0_b   = (const float*)d_in[3];
    const float* nn_w     = (const float*)d_in[4];
    const float* nn_b     = (const float*)d_in[5];
    const float* root_w   = (const float*)d_in[6];
    const float* conv_b   = (const float*)d_in[7];
    const float* gru_wi   = (const float*)d_in[8];
    const float* gru_wh   = (const float*)d_in[9];
    const float* gru_bi   = (const float*)d_in[10];
    const float* gru_bh   = (const float*)d_in[11];
    const float* lin1_w   = (const float*)d_in[12];
    const float* lin1_b   = (const float*)d_in[13];
    const int*   edge_idx = (const int*)d_in[14];
    const int*   batch    = (const int*)d_in[15];
    float* out = (float*)d_out;

    float* ws     = (float*)d_ws;
    float* feat   = ws;                        // N*32 f
    float* pooled = feat + (long)NN * 32;      // G*32 f
    float* cnt    = pooled + (long)GG * 32;    // G f
    float* Wre    = cnt + GG;                  // 5120 f
    float* wiT    = Wre + 5120;                // 3072 f
    float* whT    = wiT + 3072;                // 3072 f
    int*   row_cnt= (int*)(whT + 3072);        // 50000 i
    int*   tmp    = row_cnt + NN;              // 50000 i
    int*   bsum   = tmp + NN;                  // 256 i
    int*   row_ptr= bsum + 256;                // 50001 i
    int*   cursor = row_ptr + NN + 1;          // 50000 i
    int*   esrc   = cursor + NN;               // 100000 i
    size_t off = ((size_t)((char*)(esrc + EE) - (char*)d_ws) + 15) & ~(size_t)15;
    float4* eea  = (float4*)((char*)d_ws + off);           // 100000 float4
    unsigned short* yb = (unsigned short*)(eea + EE);      // N*160 bf16 = 16 MB
    // total ~= 28 MB

    hipMemsetAsync(pooled, 0, ((long)GG * 32 + GG) * sizeof(float), stream);
    hipMemsetAsync(row_cnt, 0, NN * sizeof(int), stream);

    k_prep<<<44, 256, 0, stream>>>(nn_w, nn_b, gru_wi, gru_wh, Wre, wiT, whT);
    k_init<<<(NN * 32 + 255) / 256, 256, 0, stream>>>(x, lin0_w, lin0_b, feat);

    // CSR build (iteration-invariant)
    k_hist<<<(EE + 255) / 256, 256, 0, stream>>>(edge_idx, row_cnt);
    k_scan1<<<NB_SCAN, 256, 0, stream>>>(row_cnt, tmp, bsum);
    k_scan2<<<1, 256, 0, stream>>>(bsum);
    k_scan3<<<NB_SCAN, 256, 0, stream>>>(row_cnt, tmp, bsum, row_ptr, cursor);
    k_scatter<<<(EE + 255) / 256, 256, 0, stream>>>(edge_idx, edge_attr, cursor, esrc, eea);

    dim3 gy((NN + 63) / 64, 4);
    for (int it = 0; it < 3; ++it) {
        k_y<<<gy, 256, 0, stream>>>(feat, Wre, yb);
        k_conv_update<<<(NN + 31) / 32, 256, 0, stream>>>(yb, row_ptr, esrc, eea,
                                                          root_w, conv_b, wiT, whT,
                                                          gru_bi, gru_bh, feat);
    }

    k_pool<<<(NN * 32 + 255) / 256, 256, 0, stream>>>(feat, batch, pooled, cnt);
    k_final<<<(GG + 255) / 256, 256, 0, stream>>>(pooled, cnt, lin1_w, lin1_b, out);
}

// Round 9
// 318.950 us; speedup vs baseline: 1.3892x; 1.0544x over previous
//
#include <hip/hip_runtime.h>
#include <hip/hip_bf16.h>

// Problem constants (from reference)
#define NN 50000
#define EE 100000
#define GG 2048
#define NB_SCAN 196   // ceil(NN/256)

__device__ __forceinline__ float b2f(unsigned short u) {
    union { unsigned int i; float f; } x; x.i = (unsigned int)u << 16; return x.f;
}
__device__ __forceinline__ unsigned short f2b(float f) {
    union { float f; unsigned int i; } x; x.f = f;
    unsigned int b = x.i + (0x7FFFu + ((x.i >> 16) & 1u));   // RNE
    return (unsigned short)(b >> 16);
}

// feat = relu(x @ lin0_w.T + lin0_b); thread per (node, out-dim)
__global__ void k_init(const float* __restrict__ x, const float* __restrict__ w,
                       const float* __restrict__ b, float* __restrict__ feat) {
    int idx = blockIdx.x * blockDim.x + threadIdx.x;
    if (idx >= NN * 32) return;
    int n = idx >> 5, o = idx & 31;
    const float* xr = x + n * 11;
    const float* wr = w + o * 11;
    float acc = b[o];
#pragma unroll
    for (int i = 0; i < 11; ++i) acc += xr[i] * wr[i];
    feat[idx] = fmaxf(acc, 0.f);
}

// Weight tables: Wre[c][i] (160x32) for k_y (wave-uniform s_load);
// wiT/whT[k][gate*32+o] (32x96) for the GRU (coalesced per-lane).
__global__ void k_prep(const float* __restrict__ nnw, const float* __restrict__ nnb,
                       const float* __restrict__ wi, const float* __restrict__ wh,
                       float* __restrict__ Wre, float* __restrict__ wiT,
                       float* __restrict__ whT) {
    int idx = blockIdx.x * blockDim.x + threadIdx.x;
    if (idx < 5120) {
        int c = idx >> 5, i = idx & 31;
        float v;
        if (c < 128) v = nnw[((i << 5) + (c & 31)) * 4 + (c >> 5)];
        else         v = nnb[(i << 5) + (c - 128)];
        Wre[idx] = v;
    } else if (idx < 8192) {
        int j = idx - 5120;
        int k = j / 96, c = j - k * 96;
        wiT[j] = wi[c * 32 + k];
    } else if (idx < 11264) {
        int j = idx - 8192;
        int k = j / 96, c = j - k * 96;
        whT[j] = wh[c * 32 + k];
    }
}

// ---- CSR build (once per launch; edges are iteration-invariant) ----
__global__ void k_hist(const int* __restrict__ ei, int* __restrict__ cnt) {
    int e = blockIdx.x * blockDim.x + threadIdx.x;
    if (e >= EE) return;
    atomicAdd(&cnt[ei[EE + e]], 1);
}

__global__ __launch_bounds__(256) void k_scan1(const int* __restrict__ cnt,
                                               int* __restrict__ tmp,
                                               int* __restrict__ bsum) {
    __shared__ int sd[256];
    int t = threadIdx.x;
    int i = blockIdx.x * 256 + t;
    int v = (i < NN) ? cnt[i] : 0;
    sd[t] = v;
    __syncthreads();
#pragma unroll
    for (int off = 1; off < 256; off <<= 1) {
        int x = (t >= off) ? sd[t - off] : 0;
        __syncthreads();
        sd[t] += x;
        __syncthreads();
    }
    if (i < NN) tmp[i] = sd[t];
    if (t == 255) bsum[blockIdx.x] = sd[255];
}

__global__ __launch_bounds__(256) void k_scan2(int* __restrict__ bsum) {
    __shared__ int sd[256];
    int t = threadIdx.x;
    int v = (t < NB_SCAN) ? bsum[t] : 0;
    sd[t] = v;
    __syncthreads();
#pragma unroll
    for (int off = 1; off < 256; off <<= 1) {
        int x = (t >= off) ? sd[t - off] : 0;
        __syncthreads();
        sd[t] += x;
        __syncthreads();
    }
    if (t < NB_SCAN) bsum[t] = sd[t];
}

__global__ void k_scan3(const int* __restrict__ cnt, const int* __restrict__ tmp,
                        const int* __restrict__ bsum, int* __restrict__ row_ptr,
                        int* __restrict__ cursor) {
    int i = blockIdx.x * blockDim.x + threadIdx.x;
    if (i >= NN) return;
    int base = (blockIdx.x > 0) ? bsum[blockIdx.x - 1] : 0;
    int excl = base + tmp[i] - cnt[i];
    row_ptr[i] = excl;
    cursor[i] = excl;
    if (i == 0) row_ptr[NN] = EE;
}

__global__ void k_scatter(const int* __restrict__ ei, const float* __restrict__ ea,
                          int* __restrict__ cursor, int* __restrict__ esrc,
                          float4* __restrict__ eea) {
    int e = blockIdx.x * blockDim.x + threadIdx.x;
    if (e >= EE) return;
    int d = ei[EE + e];
    int slot = atomicAdd(&cursor[d], 1);
    esrc[slot] = ei[e];
    eea[slot] = make_float4(ea[e * 4 + 0], ea[e * 4 + 1], ea[e * 4 + 2], ea[e * 4 + 3]);
}

// y[n,c] = sum_i feat[n,i] * Wre[c*32+i]; lane = node, wave-uniform weights
// (s_load), wave computes a 10-col slice; output stored as bf16.
__global__ __launch_bounds__(256) void k_y(const float* __restrict__ feat,
                                           const float* __restrict__ Wre,
                                           unsigned short* __restrict__ yb) {
    int lane = threadIdx.x & 63;
    int wv = __builtin_amdgcn_readfirstlane(threadIdx.x >> 6);
    int n = blockIdx.x * 64 + lane;
    if (n >= NN) return;
    int c0 = blockIdx.y * 40 + wv * 10;
    float fr[32];
    const float4* f4 = (const float4*)(feat + (long)n * 32);
#pragma unroll
    for (int q = 0; q < 8; ++q) {
        float4 v = f4[q];
        fr[4 * q + 0] = v.x; fr[4 * q + 1] = v.y;
        fr[4 * q + 2] = v.z; fr[4 * q + 3] = v.w;
    }
    float acc[10];
#pragma unroll
    for (int cc = 0; cc < 10; ++cc) {
        const float* w = Wre + (c0 + cc) * 32;   // uniform address -> s_load
        float a = 0.f;
#pragma unroll
        for (int i = 0; i < 32; ++i) a += fr[i] * w[i];
        acc[cc] = a;
    }
    unsigned short* yr = yb + (long)n * 160 + c0;  // c0*2 bytes, 4B aligned
#pragma unroll
    for (int q = 0; q < 5; ++q) {
        unsigned int wlo = f2b(acc[2 * q]);
        unsigned int whi = f2b(acc[2 * q + 1]);
        ((unsigned int*)yr)[q] = wlo | (whi << 16);
    }
}

// Edge-parallel message: msg[slot][o] = y_b[src] + sum_f ea_f * y_f[src].
// Thread = (CSR slot, o): every random y-load issued by an independent
// thread -> latency hidden by TLP. Coalesced fp32 writes in CSR order.
__global__ __launch_bounds__(256) void k_msg(
    const unsigned short* __restrict__ yb, const int* __restrict__ esrc,
    const float4* __restrict__ eea, float* __restrict__ msg) {
    int idx = blockIdx.x * 256 + threadIdx.x;
    if (idx >= EE * 32) return;
    int slot = idx >> 5, o = idx & 31;
    int s = esrc[slot];
    float4 a = eea[slot];
    const unsigned short* yr = yb + (long)s * 160;
    float y0 = b2f(yr[o]);
    float y1 = b2f(yr[32 + o]);
    float y2 = b2f(yr[64 + o]);
    float y3 = b2f(yr[96 + o]);
    float y4 = b2f(yr[128 + o]);
    msg[idx] = y4 + a.x * y0 + a.y * y1 + a.z * y2 + a.w * y3;
}

// Fused: contiguous CSR msg-sum + root matvec + GRU.
// 32-lane group = 4 nodes (register-blocked); block = 8 groups = 32 nodes.
__global__ __launch_bounds__(256) void k_conv_update(
    const float* __restrict__ msg, const int* __restrict__ row_ptr,
    const float* __restrict__ rootw, const float* __restrict__ convb,
    const float* __restrict__ wiT, const float* __restrict__ whT,
    const float* __restrict__ bi, const float* __restrict__ bh,
    float* __restrict__ feat) {
    __shared__ float fs[32][32];
    __shared__ float ms[32][32];
    int t = threadIdx.x;
    int g = t >> 5, o = t & 31;
    int nb = blockIdx.x * 32 + g * 4;
    float f[4], m[4];
#pragma unroll
    for (int j = 0; j < 4; ++j) {
        int n = nb + j;
        bool v = (n < NN);
        f[j] = v ? feat[(long)n * 32 + o] : 0.f;
        fs[g * 4 + j][o] = f[j];
        m[j] = convb[o];
        if (v) {
            int e0 = row_ptr[n], e1 = row_ptr[n + 1];
            for (int e = e0; e < e1; ++e)
                m[j] += msg[((long)e << 5) + o];   // contiguous, pipelineable
        }
    }
    __syncthreads();
#pragma unroll 4
    for (int i = 0; i < 32; ++i) {
        float rw = rootw[i * 32 + o];
#pragma unroll
        for (int j = 0; j < 4; ++j) m[j] += fs[g * 4 + j][i] * rw;
    }
#pragma unroll
    for (int j = 0; j < 4; ++j) {
        m[j] = fmaxf(m[j], 0.f);
        ms[g * 4 + j][o] = m[j];
    }
    __syncthreads();
    float bir = bi[o], biz = bi[32 + o], bin_ = bi[64 + o];
    float bhr = bh[o], bhz = bh[32 + o], bhn = bh[64 + o];
    float gir[4], giz[4], gin_[4], ghr[4], ghz[4], ghn[4];
#pragma unroll
    for (int j = 0; j < 4; ++j) {
        gir[j] = bir; giz[j] = biz; gin_[j] = bin_;
        ghr[j] = bhr; ghz[j] = bhz; ghn[j] = bhn;
    }
#pragma unroll 2
    for (int k = 0; k < 32; ++k) {
        const float* wik = wiT + k * 96 + o;
        const float* whk = whT + k * 96 + o;
        float wir = wik[0], wiz = wik[32], win = wik[64];
        float whr = whk[0], whz = whk[32], whn = whk[64];
#pragma unroll
        for (int j = 0; j < 4; ++j) {
            float mk = ms[g * 4 + j][k], hk = fs[g * 4 + j][k];
            gir[j] += mk * wir;
            giz[j] += mk * wiz;
            gin_[j] += mk * win;
            ghr[j] += hk * whr;
            ghz[j] += hk * whz;
            ghn[j] += hk * whn;
        }
    }
#pragma unroll
    for (int j = 0; j < 4; ++j) {
        int n = nb + j;
        if (n < NN) {
            float r = 1.f / (1.f + __expf(-(gir[j] + ghr[j])));
            float z = 1.f / (1.f + __expf(-(giz[j] + ghz[j])));
            float nt = tanhf(gin_[j] + r * ghn[j]);
            feat[(long)n * 32 + o] = (1.f - z) * nt + z * f[j];
        }
    }
}

// Mean-pool: per-block LDS segment-reduction over sorted batch, then
// one atomic per segment per o (~6x fewer atomics than per-element).
__global__ __launch_bounds__(256) void k_pool(const float* __restrict__ feat,
                                              const int* __restrict__ batch,
                                              float* __restrict__ pooled,
                                              float* __restrict__ cnt) {
    __shared__ float sd[8][32];
    __shared__ int sg[8];
    int t = threadIdx.x;
    int l = t >> 5, o = t & 31;
    long n = (long)blockIdx.x * 8 + l;   // 50000 = 6250*8
    sd[l][o] = feat[n * 32 + o];
    if (o == 0) sg[l] = batch[n];
    __syncthreads();
    if (l == 0) {
        float acc = sd[0][o];
        int cg = sg[0];
        int cc = 1;
#pragma unroll
        for (int r = 1; r < 8; ++r) {
            if (sg[r] == cg) { acc += sd[r][o]; ++cc; }
            else {
                atomicAdd(pooled + (long)cg * 32 + o, acc);
                if (o == 0) atomicAdd(cnt + cg, (float)cc);
                acc = sd[r][o]; cg = sg[r]; cc = 1;
            }
        }
        atomicAdd(pooled + (long)cg * 32 + o, acc);
        if (o == 0) atomicAdd(cnt + cg, (float)cc);
    }
}

// logits = (pooled/cnt) @ lin1_w.T + lin1_b; log_softmax over 2 classes
__global__ void k_final(const float* __restrict__ pooled, const float* __restrict__ cnt,
                        const float* __restrict__ w, const float* __restrict__ b,
                        float* __restrict__ out) {
    int g = blockIdx.x * blockDim.x + threadIdx.x;
    if (g >= GG) return;
    float inv = 1.f / fmaxf(cnt[g], 1.f);
    float l0 = b[0], l1 = b[1];
    const float* pr = pooled + g * 32;
#pragma unroll
    for (int k = 0; k < 32; ++k) {
        float p = pr[k] * inv;
        l0 += p * w[k];
        l1 += p * w[32 + k];
    }
    float mx = fmaxf(l0, l1);
    float lse = mx + logf(__expf(l0 - mx) + __expf(l1 - mx));
    out[g * 2 + 0] = l0 - lse;
    out[g * 2 + 1] = l1 - lse;
}

extern "C" void kernel_launch(void* const* d_in, const int* in_sizes, int n_in,
                              void* d_out, int out_size, void* d_ws, size_t ws_size,
                              hipStream_t stream) {
    const float* x        = (const float*)d_in[0];
    const float* edge_attr= (const float*)d_in[1];
    const float* lin0_w   = (const float*)d_in[2];
    const float* lin0_b   = (const float*)d_in[3];
    const float* nn_w     = (const float*)d_in[4];
    const float* nn_b     = (const float*)d_in[5];
    const float* root_w   = (const float*)d_in[6];
    const float* conv_b   = (const float*)d_in[7];
    const float* gru_wi   = (const float*)d_in[8];
    const float* gru_wh   = (const float*)d_in[9];
    const float* gru_bi   = (const float*)d_in[10];
    const float* gru_bh   = (const float*)d_in[11];
    const float* lin1_w   = (const float*)d_in[12];
    const float* lin1_b   = (const float*)d_in[13];
    const int*   edge_idx = (const int*)d_in[14];
    const int*   batch    = (const int*)d_in[15];
    float* out = (float*)d_out;

    float* ws     = (float*)d_ws;
    float* feat   = ws;                        // N*32 f
    float* pooled = feat + (long)NN * 32;      // G*32 f
    float* cnt    = pooled + (long)GG * 32;    // G f
    float* Wre    = cnt + GG;                  // 5120 f
    float* wiT    = Wre + 5120;                // 3072 f
    float* whT    = wiT + 3072;                // 3072 f
    int*   row_cnt= (int*)(whT + 3072);        // 50000 i
    int*   tmp    = row_cnt + NN;              // 50000 i
    int*   bsum   = tmp + NN;                  // 256 i
    int*   row_ptr= bsum + 256;                // 50001 i
    int*   cursor = row_ptr + NN + 1;          // 50000 i
    int*   esrc   = cursor + NN;               // 100000 i
    size_t off = ((size_t)((char*)(esrc + EE) - (char*)d_ws) + 15) & ~(size_t)15;
    float4* eea  = (float4*)((char*)d_ws + off);           // 100000 float4
    unsigned short* yb = (unsigned short*)(eea + EE);      // N*160 bf16 = 16 MB
    float* msg   = (float*)(yb + (long)NN * 160);          // E*32 f = 12.8 MB
    // total ~= 41 MB

    hipMemsetAsync(pooled, 0, ((long)GG * 32 + GG) * sizeof(float), stream);
    hipMemsetAsync(row_cnt, 0, NN * sizeof(int), stream);

    k_prep<<<44, 256, 0, stream>>>(nn_w, nn_b, gru_wi, gru_wh, Wre, wiT, whT);
    k_init<<<(NN * 32 + 255) / 256, 256, 0, stream>>>(x, lin0_w, lin0_b, feat);

    // CSR build (iteration-invariant)
    k_hist<<<(EE + 255) / 256, 256, 0, stream>>>(edge_idx, row_cnt);
    k_scan1<<<NB_SCAN, 256, 0, stream>>>(row_cnt, tmp, bsum);
    k_scan2<<<1, 256, 0, stream>>>(bsum);
    k_scan3<<<NB_SCAN, 256, 0, stream>>>(row_cnt, tmp, bsum, row_ptr, cursor);
    k_scatter<<<(EE + 255) / 256, 256, 0, stream>>>(edge_idx, edge_attr, cursor, esrc, eea);

    dim3 gy((NN + 63) / 64, 4);
    for (int it = 0; it < 3; ++it) {
        k_y<<<gy, 256, 0, stream>>>(feat, Wre, yb);
        k_msg<<<(EE * 32 + 255) / 256, 256, 0, stream>>>(yb, esrc, eea, msg);
        k_conv_update<<<(NN + 31) / 32, 256, 0, stream>>>(msg, row_ptr,
                                                          root_w, conv_b, wiT, whT,
                                                          gru_bi, gru_bh, feat);
    }

    k_pool<<<NN / 8, 256, 0, stream>>>(feat, batch, pooled, cnt);
    k_final<<<(GG + 255) / 256, 256, 0, stream>>>(pooled, cnt, lin1_w, lin1_b, out);
}

// Round 10
// 304.910 us; speedup vs baseline: 1.4532x; 1.0460x over previous
//
#include <hip/hip_runtime.h>
#include <hip/hip_bf16.h>

// Problem constants (from reference)
#define NN 50000
#define EE 100000
#define GG 2048
#define NB_SCAN 196   // ceil(NN/256)

__device__ __forceinline__ float b2f(unsigned short u) {
    union { unsigned int i; float f; } x; x.i = (unsigned int)u << 16; return x.f;
}
__device__ __forceinline__ unsigned short f2b(float f) {
    union { float f; unsigned int i; } x; x.f = f;
    unsigned int b = x.i + (0x7FFFu + ((x.i >> 16) & 1u));   // RNE
    return (unsigned short)(b >> 16);
}

// feat = relu(x @ lin0_w.T + lin0_b); thread per (node, out-dim)
__global__ void k_init(const float* __restrict__ x, const float* __restrict__ w,
                       const float* __restrict__ b, float* __restrict__ feat) {
    int idx = blockIdx.x * blockDim.x + threadIdx.x;
    if (idx >= NN * 32) return;
    int n = idx >> 5, o = idx & 31;
    const float* xr = x + n * 11;
    const float* wr = w + o * 11;
    float acc = b[o];
#pragma unroll
    for (int i = 0; i < 11; ++i) acc += xr[i] * wr[i];
    feat[idx] = fmaxf(acc, 0.f);
}

// Weight tables:
//  Wre [c][i] (160x32): k_y, wave-uniform s_load
//  WyT [i][c] (32x160): fused-y in conv_update, coalesced per-lane
//  wiT/whT [k][gate*32+o] (32x96): GRU, coalesced per-lane
__global__ void k_prep(const float* __restrict__ nnw, const float* __restrict__ nnb,
                       const float* __restrict__ wi, const float* __restrict__ wh,
                       float* __restrict__ Wre, float* __restrict__ WyT,
                       float* __restrict__ wiT, float* __restrict__ whT) {
    int idx = blockIdx.x * blockDim.x + threadIdx.x;
    if (idx < 5120) {
        int c = idx >> 5, i = idx & 31;
        float v;
        if (c < 128) v = nnw[((i << 5) + (c & 31)) * 4 + (c >> 5)];
        else         v = nnb[(i << 5) + (c - 128)];
        Wre[idx] = v;
    } else if (idx < 10240) {
        int j = idx - 5120;
        int i = j / 160, c = j - i * 160;
        float v;
        if (c < 128) v = nnw[((i << 5) + (c & 31)) * 4 + (c >> 5)];
        else         v = nnb[(i << 5) + (c - 128)];
        WyT[j] = v;
    } else if (idx < 13312) {
        int j = idx - 10240;
        int k = j / 96, c = j - k * 96;
        wiT[j] = wi[c * 32 + k];
    } else if (idx < 16384) {
        int j = idx - 13312;
        int k = j / 96, c = j - k * 96;
        whT[j] = wh[c * 32 + k];
    }
}

// ---- CSR build (once per launch; edges are iteration-invariant) ----
__global__ void k_hist(const int* __restrict__ ei, int* __restrict__ cnt) {
    int e = blockIdx.x * blockDim.x + threadIdx.x;
    if (e >= EE) return;
    atomicAdd(&cnt[ei[EE + e]], 1);
}

__global__ __launch_bounds__(256) void k_scan1(const int* __restrict__ cnt,
                                               int* __restrict__ tmp,
                                               int* __restrict__ bsum) {
    __shared__ int sd[256];
    int t = threadIdx.x;
    int i = blockIdx.x * 256 + t;
    int v = (i < NN) ? cnt[i] : 0;
    sd[t] = v;
    __syncthreads();
#pragma unroll
    for (int off = 1; off < 256; off <<= 1) {
        int x = (t >= off) ? sd[t - off] : 0;
        __syncthreads();
        sd[t] += x;
        __syncthreads();
    }
    if (i < NN) tmp[i] = sd[t];
    if (t == 255) bsum[blockIdx.x] = sd[255];
}

__global__ __launch_bounds__(256) void k_scan2(int* __restrict__ bsum) {
    __shared__ int sd[256];
    int t = threadIdx.x;
    int v = (t < NB_SCAN) ? bsum[t] : 0;
    sd[t] = v;
    __syncthreads();
#pragma unroll
    for (int off = 1; off < 256; off <<= 1) {
        int x = (t >= off) ? sd[t - off] : 0;
        __syncthreads();
        sd[t] += x;
        __syncthreads();
    }
    if (t < NB_SCAN) bsum[t] = sd[t];
}

__global__ void k_scan3(const int* __restrict__ cnt, const int* __restrict__ tmp,
                        const int* __restrict__ bsum, int* __restrict__ row_ptr,
                        int* __restrict__ cursor) {
    int i = blockIdx.x * blockDim.x + threadIdx.x;
    if (i >= NN) return;
    int base = (blockIdx.x > 0) ? bsum[blockIdx.x - 1] : 0;
    int excl = base + tmp[i] - cnt[i];
    row_ptr[i] = excl;
    cursor[i] = excl;
    if (i == 0) row_ptr[NN] = EE;
}

__global__ void k_scatter(const int* __restrict__ ei, const float* __restrict__ ea,
                          int* __restrict__ cursor, int* __restrict__ esrc,
                          float4* __restrict__ eea) {
    int e = blockIdx.x * blockDim.x + threadIdx.x;
    if (e >= EE) return;
    int d = ei[EE + e];
    int slot = atomicAdd(&cursor[d], 1);
    esrc[slot] = ei[e];
    eea[slot] = make_float4(ea[e * 4 + 0], ea[e * 4 + 1], ea[e * 4 + 2], ea[e * 4 + 3]);
}

// Initial y table (runs ONCE, on k_init's feat). Lane = node, wave-uniform
// weights via s_load, wave computes a 10-col slice; bf16 output.
__global__ __launch_bounds__(256) void k_y(const float* __restrict__ feat,
                                           const float* __restrict__ Wre,
                                           unsigned short* __restrict__ yb) {
    int lane = threadIdx.x & 63;
    int wv = __builtin_amdgcn_readfirstlane(threadIdx.x >> 6);
    int n = blockIdx.x * 64 + lane;
    if (n >= NN) return;
    int c0 = blockIdx.y * 40 + wv * 10;
    float fr[32];
    const float4* f4 = (const float4*)(feat + (long)n * 32);
#pragma unroll
    for (int q = 0; q < 8; ++q) {
        float4 v = f4[q];
        fr[4 * q + 0] = v.x; fr[4 * q + 1] = v.y;
        fr[4 * q + 2] = v.z; fr[4 * q + 3] = v.w;
    }
    float acc[10];
#pragma unroll
    for (int cc = 0; cc < 10; ++cc) {
        const float* w = Wre + (c0 + cc) * 32;   // uniform address -> s_load
        float a = 0.f;
#pragma unroll
        for (int i = 0; i < 32; ++i) a += fr[i] * w[i];
        acc[cc] = a;
    }
    unsigned short* yr = yb + (long)n * 160 + c0;
#pragma unroll
    for (int q = 0; q < 5; ++q) {
        unsigned int wlo = f2b(acc[2 * q]);
        unsigned int whi = f2b(acc[2 * q + 1]);
        ((unsigned int*)yr)[q] = wlo | (whi << 16);
    }
}

// Edge-parallel message: msg[slot][o] = y_b[src] + sum_f ea_f * y_f[src].
__global__ __launch_bounds__(256) void k_msg(
    const unsigned short* __restrict__ yb, const int* __restrict__ esrc,
    const float4* __restrict__ eea, float* __restrict__ msg) {
    int idx = blockIdx.x * 256 + threadIdx.x;
    if (idx >= EE * 32) return;
    int slot = idx >> 5, o = idx & 31;
    int s = esrc[slot];
    float4 a = eea[slot];
    const unsigned short* yr = yb + (long)s * 160;
    float y0 = b2f(yr[o]);
    float y1 = b2f(yr[32 + o]);
    float y2 = b2f(yr[64 + o]);
    float y3 = b2f(yr[96 + o]);
    float y4 = b2f(yr[128 + o]);
    msg[idx] = y4 + a.x * y0 + a.y * y1 + a.z * y2 + a.w * y3;
}

// Fused: contiguous CSR msg-sum + root matvec + GRU + (optionally) next y.
// 32-lane group = 4 nodes (register-blocked); block = 8 groups = 32 nodes.
__global__ __launch_bounds__(256) void k_conv_update(
    const float* __restrict__ msg, const int* __restrict__ row_ptr,
    const float* __restrict__ rootw, const float* __restrict__ convb,
    const float* __restrict__ wiT, const float* __restrict__ whT,
    const float* __restrict__ bi, const float* __restrict__ bh,
    const float* __restrict__ WyT, float* __restrict__ feat,
    unsigned short* __restrict__ yb, int write_y) {
    __shared__ float fs[32][32];
    __shared__ float ms[32][32];
    int t = threadIdx.x;
    int g = t >> 5, o = t & 31;
    int nb = blockIdx.x * 32 + g * 4;
    float f[4], m[4];
#pragma unroll
    for (int j = 0; j < 4; ++j) {
        int n = nb + j;
        bool v = (n < NN);
        f[j] = v ? feat[(long)n * 32 + o] : 0.f;
        fs[g * 4 + j][o] = f[j];
        m[j] = convb[o];
        if (v) {
            int e0 = row_ptr[n], e1 = row_ptr[n + 1];
            for (int e = e0; e < e1; ++e)
                m[j] += msg[((long)e << 5) + o];   // contiguous, pipelineable
        }
    }
    __syncthreads();
#pragma unroll 4
    for (int i = 0; i < 32; ++i) {
        float rw = rootw[i * 32 + o];
#pragma unroll
        for (int j = 0; j < 4; ++j) m[j] += fs[g * 4 + j][i] * rw;
    }
#pragma unroll
    for (int j = 0; j < 4; ++j) {
        m[j] = fmaxf(m[j], 0.f);
        ms[g * 4 + j][o] = m[j];
    }
    __syncthreads();
    float bir = bi[o], biz = bi[32 + o], bin_ = bi[64 + o];
    float bhr = bh[o], bhz = bh[32 + o], bhn = bh[64 + o];
    float gir[4], giz[4], gin_[4], ghr[4], ghz[4], ghn[4];
#pragma unroll
    for (int j = 0; j < 4; ++j) {
        gir[j] = bir; giz[j] = biz; gin_[j] = bin_;
        ghr[j] = bhr; ghz[j] = bhz; ghn[j] = bhn;
    }
#pragma unroll 2
    for (int k = 0; k < 32; ++k) {
        const float* wik = wiT + k * 96 + o;
        const float* whk = whT + k * 96 + o;
        float wir = wik[0], wiz = wik[32], win = wik[64];
        float whr = whk[0], whz = whk[32], whn = whk[64];
#pragma unroll
        for (int j = 0; j < 4; ++j) {
            float mk = ms[g * 4 + j][k], hk = fs[g * 4 + j][k];
            gir[j] += mk * wir;
            giz[j] += mk * wiz;
            gin_[j] += mk * win;
            ghr[j] += hk * whr;
            ghz[j] += hk * whz;
            ghn[j] += hk * whn;
        }
    }
    float fn[4];
#pragma unroll
    for (int j = 0; j < 4; ++j) {
        int n = nb + j;
        float r = 1.f / (1.f + __expf(-(gir[j] + ghr[j])));
        float z = 1.f / (1.f + __expf(-(giz[j] + ghz[j])));
        float nt = tanhf(gin_[j] + r * ghn[j]);
        fn[j] = (1.f - z) * nt + z * f[j];
        if (n < NN) feat[(long)n * 32 + o] = fn[j];
    }
    if (!write_y) return;
    // stage NEW feat in fs (rows owned exclusively by this wave's groups;
    // within-wave LDS write->read is ordered via lgkmcnt)
#pragma unroll
    for (int j = 0; j < 4; ++j) fs[g * 4 + j][o] = fn[j];
    // y[n][f*32+o] = sum_i fs[n][i] * WyT[i*160 + f*32 + o]; 5 loads : 20 FMA
    float ya[4][5];
#pragma unroll
    for (int j = 0; j < 4; ++j)
#pragma unroll
        for (int q = 0; q < 5; ++q) ya[j][q] = 0.f;
#pragma unroll 4
    for (int i = 0; i < 32; ++i) {
        const float* wy = WyT + i * 160 + o;
        float w0 = wy[0], w1 = wy[32], w2 = wy[64], w3 = wy[96], w4 = wy[128];
#pragma unroll
        for (int j = 0; j < 4; ++j) {
            float fv = fs[g * 4 + j][i];
            ya[j][0] += fv * w0;
            ya[j][1] += fv * w1;
            ya[j][2] += fv * w2;
            ya[j][3] += fv * w3;
            ya[j][4] += fv * w4;
        }
    }
#pragma unroll
    for (int j = 0; j < 4; ++j) {
        int n = nb + j;
        if (n < NN) {
            unsigned short* yr = yb + (long)n * 160 + o;
#pragma unroll
            for (int q = 0; q < 5; ++q) yr[q * 32] = f2b(ya[j][q]);
        }
    }
}

// Fused mean-pool + classifier: one 64-thread block per graph; batch is
// sorted so the node range comes from two binary searches; wave shuffles
// do the mean and the 2-logit dot + log_softmax. No atomics, no memset.
__global__ __launch_bounds__(64) void k_pool_final(
    const float* __restrict__ feat, const int* __restrict__ batch,
    const float* __restrict__ w, const float* __restrict__ b,
    float* __restrict__ out) {
    int g = blockIdx.x;
    int t = threadIdx.x;
    int o = t & 31, h = t >> 5;
    int lo = 0, hi = NN;
    while (lo < hi) { int mid = (lo + hi) >> 1; if (batch[mid] < g) lo = mid + 1; else hi = mid; }
    int start = lo;
    hi = NN;
    while (lo < hi) { int mid = (lo + hi) >> 1; if (batch[mid] <= g) lo = mid + 1; else hi = mid; }
    int end = lo;
    float acc = 0.f;
    for (int n = start + h; n < end; n += 2) acc += feat[(long)n * 32 + o];
    acc += __shfl_xor(acc, 32, 64);
    float p = acc / fmaxf((float)(end - start), 1.f);
    float l0 = p * w[o], l1 = p * w[32 + o];
#pragma unroll
    for (int s = 16; s >= 1; s >>= 1) {
        l0 += __shfl_xor(l0, s, 64);
        l1 += __shfl_xor(l1, s, 64);
    }
    if (t == 0) {
        l0 += b[0]; l1 += b[1];
        float mx = fmaxf(l0, l1);
        float lse = mx + logf(__expf(l0 - mx) + __expf(l1 - mx));
        out[g * 2 + 0] = l0 - lse;
        out[g * 2 + 1] = l1 - lse;
    }
}

extern "C" void kernel_launch(void* const* d_in, const int* in_sizes, int n_in,
                              void* d_out, int out_size, void* d_ws, size_t ws_size,
                              hipStream_t stream) {
    const float* x        = (const float*)d_in[0];
    const float* edge_attr= (const float*)d_in[1];
    const float* lin0_w   = (const float*)d_in[2];
    const float* lin0_b   = (const float*)d_in[3];
    const float* nn_w     = (const float*)d_in[4];
    const float* nn_b     = (const float*)d_in[5];
    const float* root_w   = (const float*)d_in[6];
    const float* conv_b   = (const float*)d_in[7];
    const float* gru_wi   = (const float*)d_in[8];
    const float* gru_wh   = (const float*)d_in[9];
    const float* gru_bi   = (const float*)d_in[10];
    const float* gru_bh   = (const float*)d_in[11];
    const float* lin1_w   = (const float*)d_in[12];
    const float* lin1_b   = (const float*)d_in[13];
    const int*   edge_idx = (const int*)d_in[14];
    const int*   batch    = (const int*)d_in[15];
    float* out = (float*)d_out;

    float* ws     = (float*)d_ws;
    float* feat   = ws;                        // N*32 f
    float* Wre    = feat + (long)NN * 32;      // 5120 f
    float* WyT    = Wre + 5120;                // 5120 f
    float* wiT    = WyT + 5120;                // 3072 f
    float* whT    = wiT + 3072;                // 3072 f
    int*   row_cnt= (int*)(whT + 3072);        // 50000 i
    int*   tmp    = row_cnt + NN;              // 50000 i
    int*   bsum   = tmp + NN;                  // 256 i
    int*   row_ptr= bsum + 256;                // 50001 i
    int*   cursor = row_ptr + NN + 1;          // 50000 i
    int*   esrc   = cursor + NN;               // 100000 i
    size_t off = ((size_t)((char*)(esrc + EE) - (char*)d_ws) + 15) & ~(size_t)15;
    float4* eea  = (float4*)((char*)d_ws + off);           // 100000 float4
    unsigned short* yb = (unsigned short*)(eea + EE);      // N*160 bf16 = 16 MB
    float* msg   = (float*)(yb + (long)NN * 160);          // E*32 f = 12.8 MB
    // total ~= 41 MB

    hipMemsetAsync(row_cnt, 0, NN * sizeof(int), stream);

    k_prep<<<64, 256, 0, stream>>>(nn_w, nn_b, gru_wi, gru_wh, Wre, WyT, wiT, whT);
    k_init<<<(NN * 32 + 255) / 256, 256, 0, stream>>>(x, lin0_w, lin0_b, feat);

    // CSR build (iteration-invariant)
    k_hist<<<(EE + 255) / 256, 256, 0, stream>>>(edge_idx, row_cnt);
    k_scan1<<<NB_SCAN, 256, 0, stream>>>(row_cnt, tmp, bsum);
    k_scan2<<<1, 256, 0, stream>>>(bsum);
    k_scan3<<<NB_SCAN, 256, 0, stream>>>(row_cnt, tmp, bsum, row_ptr, cursor);
    k_scatter<<<(EE + 255) / 256, 256, 0, stream>>>(edge_idx, edge_attr, cursor, esrc, eea);

    dim3 gy((NN + 63) / 64, 4);
    k_y<<<gy, 256, 0, stream>>>(feat, Wre, yb);
    for (int it = 0; it < 3; ++it) {
        k_msg<<<(EE * 32 + 255) / 256, 256, 0, stream>>>(yb, esrc, eea, msg);
        k_conv_update<<<(NN + 31) / 32, 256, 0, stream>>>(msg, row_ptr,
                                                          root_w, conv_b, wiT, whT,
                                                          gru_bi, gru_bh, WyT,
                                                          feat, yb, it < 2 ? 1 : 0);
    }

    k_pool_final<<<GG, 64, 0, stream>>>(feat, batch, lin1_w, lin1_b, out);
}

// Round 11
// 292.985 us; speedup vs baseline: 1.5124x; 1.0407x over previous
//
#include <hip/hip_runtime.h>
#include <hip/hip_bf16.h>

// Problem constants (from reference)
#define NN 50000
#define EE 100000
#define GG 2048
#define NB2 391   // ceil(2*NN/256) for the dual (dst|src) scan

__device__ __forceinline__ float b2f(unsigned short u) {
    union { unsigned int i; float f; } x; x.i = (unsigned int)u << 16; return x.f;
}
__device__ __forceinline__ unsigned short f2b(float f) {
    union { float f; unsigned int i; } x; x.f = f;
    unsigned int b = x.i + (0x7FFFu + ((x.i >> 16) & 1u));   // RNE
    return (unsigned short)(b >> 16);
}

// feat = relu(x @ lin0_w.T + lin0_b); thread per (node, out-dim)
__global__ void k_init(const float* __restrict__ x, const float* __restrict__ w,
                       const float* __restrict__ b, float* __restrict__ feat) {
    int idx = blockIdx.x * blockDim.x + threadIdx.x;
    if (idx >= NN * 32) return;
    int n = idx >> 5, o = idx & 31;
    const float* xr = x + n * 11;
    const float* wr = w + o * 11;
    float acc = b[o];
#pragma unroll
    for (int i = 0; i < 11; ++i) acc += xr[i] * wr[i];
    feat[idx] = fmaxf(acc, 0.f);
}

// Weight tables:
//  Wre [c][i] (160x32): k_y, wave-uniform s_load
//  WyT [i][c] (32x160): fused-y in conv_update, coalesced per-lane
//  wiT/whT [k][gate*32+o] (32x96): GRU, coalesced per-lane
__global__ void k_prep(const float* __restrict__ nnw, const float* __restrict__ nnb,
                       const float* __restrict__ wi, const float* __restrict__ wh,
                       float* __restrict__ Wre, float* __restrict__ WyT,
                       float* __restrict__ wiT, float* __restrict__ whT) {
    int idx = blockIdx.x * blockDim.x + threadIdx.x;
    if (idx < 5120) {
        int c = idx >> 5, i = idx & 31;
        float v;
        if (c < 128) v = nnw[((i << 5) + (c & 31)) * 4 + (c >> 5)];
        else         v = nnb[(i << 5) + (c - 128)];
        Wre[idx] = v;
    } else if (idx < 10240) {
        int j = idx - 5120;
        int i = j / 160, c = j - i * 160;
        float v;
        if (c < 128) v = nnw[((i << 5) + (c & 31)) * 4 + (c >> 5)];
        else         v = nnb[(i << 5) + (c - 128)];
        WyT[j] = v;
    } else if (idx < 13312) {
        int j = idx - 10240;
        int k = j / 96, c = j - k * 96;
        wiT[j] = wi[c * 32 + k];
    } else if (idx < 16384) {
        int j = idx - 13312;
        int k = j / 96, c = j - k * 96;
        whT[j] = wh[c * 32 + k];
    }
}

// ---- CSR (by dst) + CSC (by src) build, once per launch ----
// cnt[0..NN) = in-degree (dst), cnt[NN..2NN) = out-degree (src)
__global__ void k_hist(const int* __restrict__ ei, int* __restrict__ cnt) {
    int e = blockIdx.x * blockDim.x + threadIdx.x;
    if (e >= EE) return;
    atomicAdd(&cnt[ei[EE + e]], 1);
    atomicAdd(&cnt[NN + ei[e]], 1);
}

__global__ __launch_bounds__(256) void k_scan1(const int* __restrict__ cnt,
                                               int* __restrict__ tmp,
                                               int* __restrict__ bsum) {
    __shared__ int sd[256];
    int t = threadIdx.x;
    int i = blockIdx.x * 256 + t;
    int v = (i < 2 * NN) ? cnt[i] : 0;
    sd[t] = v;
    __syncthreads();
#pragma unroll
    for (int off = 1; off < 256; off <<= 1) {
        int x = (t >= off) ? sd[t - off] : 0;
        __syncthreads();
        sd[t] += x;
        __syncthreads();
    }
    if (i < 2 * NN) tmp[i] = sd[t];
    if (t == 255) bsum[blockIdx.x] = sd[255];
}

__global__ __launch_bounds__(512) void k_scan2(int* __restrict__ bsum) {
    __shared__ int sd[512];
    int t = threadIdx.x;
    int v = (t < NB2) ? bsum[t] : 0;
    sd[t] = v;
    __syncthreads();
#pragma unroll
    for (int off = 1; off < 512; off <<= 1) {
        int x = (t >= off) ? sd[t - off] : 0;
        __syncthreads();
        sd[t] += x;
        __syncthreads();
    }
    if (t < NB2) bsum[t] = sd[t];
}

// first half -> row_ptr/cursor (dst CSR); second half -> out_ptr/cursor2
// (src CSC; subtract EE since it sits after all dst counts in the scan)
__global__ void k_scan3(const int* __restrict__ cnt, const int* __restrict__ tmp,
                        const int* __restrict__ bsum, int* __restrict__ row_ptr,
                        int* __restrict__ cursor, int* __restrict__ out_ptr,
                        int* __restrict__ cursor2) {
    int i = blockIdx.x * blockDim.x + threadIdx.x;
    if (i >= 2 * NN) return;
    int base = (blockIdx.x > 0) ? bsum[blockIdx.x - 1] : 0;
    int excl = base + tmp[i] - cnt[i];
    if (i < NN) {
        row_ptr[i] = excl;
        cursor[i] = excl;
        if (i == 0) row_ptr[NN] = EE;
    } else {
        int j = i - NN;
        out_ptr[j] = excl - EE;
        cursor2[j] = excl - EE;
        if (j == 0) out_ptr[NN] = EE;
    }
}

// place each edge into dst-CSR (esrc,eea) and src-CSC (oslot,oea)
__global__ void k_scatter(const int* __restrict__ ei, const float* __restrict__ ea,
                          int* __restrict__ cursor, int* __restrict__ cursor2,
                          int* __restrict__ esrc, float4* __restrict__ eea,
                          int* __restrict__ oslot, float4* __restrict__ oea) {
    int e = blockIdx.x * blockDim.x + threadIdx.x;
    if (e >= EE) return;
    int s = ei[e], d = ei[EE + e];
    float4 a = make_float4(ea[e * 4 + 0], ea[e * 4 + 1], ea[e * 4 + 2], ea[e * 4 + 3]);
    int slot = atomicAdd(&cursor[d], 1);
    esrc[slot] = s;
    eea[slot] = a;
    int pos = atomicAdd(&cursor2[s], 1);
    oslot[pos] = slot;
    oea[pos] = a;
}

// Initial y table (prologue only, on k_init's feat). Lane = node, wave-uniform
// weights via s_load, wave computes a 10-col slice; bf16 output.
__global__ __launch_bounds__(256) void k_y(const float* __restrict__ feat,
                                           const float* __restrict__ Wre,
                                           unsigned short* __restrict__ yb) {
    int lane = threadIdx.x & 63;
    int wv = __builtin_amdgcn_readfirstlane(threadIdx.x >> 6);
    int n = blockIdx.x * 64 + lane;
    if (n >= NN) return;
    int c0 = blockIdx.y * 40 + wv * 10;
    float fr[32];
    const float4* f4 = (const float4*)(feat + (long)n * 32);
#pragma unroll
    for (int q = 0; q < 8; ++q) {
        float4 v = f4[q];
        fr[4 * q + 0] = v.x; fr[4 * q + 1] = v.y;
        fr[4 * q + 2] = v.z; fr[4 * q + 3] = v.w;
    }
    float acc[10];
#pragma unroll
    for (int cc = 0; cc < 10; ++cc) {
        const float* w = Wre + (c0 + cc) * 32;   // uniform address -> s_load
        float a = 0.f;
#pragma unroll
        for (int i = 0; i < 32; ++i) a += fr[i] * w[i];
        acc[cc] = a;
    }
    unsigned short* yr = yb + (long)n * 160 + c0;
#pragma unroll
    for (int q = 0; q < 5; ++q) {
        unsigned int wlo = f2b(acc[2 * q]);
        unsigned int whi = f2b(acc[2 * q + 1]);
        ((unsigned int*)yr)[q] = wlo | (whi << 16);
    }
}

// Prologue edge-parallel message (iteration 0 only).
__global__ __launch_bounds__(256) void k_msg(
    const unsigned short* __restrict__ yb, const int* __restrict__ esrc,
    const float4* __restrict__ eea, float* __restrict__ msg) {
    int idx = blockIdx.x * 256 + threadIdx.x;
    if (idx >= EE * 32) return;
    int slot = idx >> 5, o = idx & 31;
    int s = esrc[slot];
    float4 a = eea[slot];
    const unsigned short* yr = yb + (long)s * 160;
    float y0 = b2f(yr[o]);
    float y1 = b2f(yr[32 + o]);
    float y2 = b2f(yr[64 + o]);
    float y3 = b2f(yr[96 + o]);
    float y4 = b2f(yr[128 + o]);
    msg[idx] = y4 + a.x * y0 + a.y * y1 + a.z * y2 + a.w * y3;
}

// Fused: contiguous CSR msg-sum + root matvec + GRU + next-iter msg via CSC.
// 32-lane group = 4 nodes (register-blocked); block = 8 groups = 32 nodes.
// Reads msg_in (this iter), writes msg_out (next iter) - ping-pong buffers.
__global__ __launch_bounds__(256) void k_conv_update(
    const float* __restrict__ msg_in, const int* __restrict__ row_ptr,
    const float* __restrict__ rootw, const float* __restrict__ convb,
    const float* __restrict__ wiT, const float* __restrict__ whT,
    const float* __restrict__ bi, const float* __restrict__ bh,
    const float* __restrict__ WyT, const int* __restrict__ out_ptr,
    const int* __restrict__ oslot, const float4* __restrict__ oea,
    float* __restrict__ feat, float* __restrict__ msg_out, int write_msg) {
    __shared__ float fs[32][32];
    __shared__ float ms[32][32];
    int t = threadIdx.x;
    int g = t >> 5, o = t & 31;
    int nb = blockIdx.x * 32 + g * 4;
    float f[4], m[4];
#pragma unroll
    for (int j = 0; j < 4; ++j) {
        int n = nb + j;
        bool v = (n < NN);
        f[j] = v ? feat[(long)n * 32 + o] : 0.f;
        fs[g * 4 + j][o] = f[j];
        m[j] = convb[o];
        if (v) {
            int e0 = row_ptr[n], e1 = row_ptr[n + 1];
            for (int e = e0; e < e1; ++e)
                m[j] += msg_in[((long)e << 5) + o];   // contiguous, pipelineable
        }
    }
    __syncthreads();
#pragma unroll 4
    for (int i = 0; i < 32; ++i) {
        float rw = rootw[i * 32 + o];
#pragma unroll
        for (int j = 0; j < 4; ++j) m[j] += fs[g * 4 + j][i] * rw;
    }
#pragma unroll
    for (int j = 0; j < 4; ++j) {
        m[j] = fmaxf(m[j], 0.f);
        ms[g * 4 + j][o] = m[j];
    }
    __syncthreads();
    float bir = bi[o], biz = bi[32 + o], bin_ = bi[64 + o];
    float bhr = bh[o], bhz = bh[32 + o], bhn = bh[64 + o];
    float gir[4], giz[4], gin_[4], ghr[4], ghz[4], ghn[4];
#pragma unroll
    for (int j = 0; j < 4; ++j) {
        gir[j] = bir; giz[j] = biz; gin_[j] = bin_;
        ghr[j] = bhr; ghz[j] = bhz; ghn[j] = bhn;
    }
#pragma unroll 2
    for (int k = 0; k < 32; ++k) {
        const float* wik = wiT + k * 96 + o;
        const float* whk = whT + k * 96 + o;
        float wir = wik[0], wiz = wik[32], win = wik[64];
        float whr = whk[0], whz = whk[32], whn = whk[64];
#pragma unroll
        for (int j = 0; j < 4; ++j) {
            float mk = ms[g * 4 + j][k], hk = fs[g * 4 + j][k];
            gir[j] += mk * wir;
            giz[j] += mk * wiz;
            gin_[j] += mk * win;
            ghr[j] += hk * whr;
            ghz[j] += hk * whz;
            ghn[j] += hk * whn;
        }
    }
    float fn[4];
#pragma unroll
    for (int j = 0; j < 4; ++j) {
        int n = nb + j;
        float r = 1.f / (1.f + __expf(-(gir[j] + ghr[j])));
        float z = 1.f / (1.f + __expf(-(giz[j] + ghz[j])));
        float nt = tanhf(gin_[j] + r * ghn[j]);
        fn[j] = (1.f - z) * nt + z * f[j];
        if (n < NN) feat[(long)n * 32 + o] = fn[j];
    }
    if (!write_msg) return;
    // stage NEW feat (rows owned by this wave; same-wave LDS ordering ok)
#pragma unroll
    for (int j = 0; j < 4; ++j) fs[g * 4 + j][o] = fn[j];
    // y row in registers: ya[j][q] = sum_i fs[n][i] * WyT[i*160 + q*32 + o]
    float ya[4][5];
#pragma unroll
    for (int j = 0; j < 4; ++j)
#pragma unroll
        for (int q = 0; q < 5; ++q) ya[j][q] = 0.f;
#pragma unroll 4
    for (int i = 0; i < 32; ++i) {
        const float* wy = WyT + i * 160 + o;
        float w0 = wy[0], w1 = wy[32], w2 = wy[64], w3 = wy[96], w4 = wy[128];
#pragma unroll
        for (int j = 0; j < 4; ++j) {
            float fv = fs[g * 4 + j][i];
            ya[j][0] += fv * w0;
            ya[j][1] += fv * w1;
            ya[j][2] += fv * w2;
            ya[j][3] += fv * w3;
            ya[j][4] += fv * w4;
        }
    }
    // next-iter msg straight to dst-CSR slots (coalesced 128B per edge)
#pragma unroll
    for (int j = 0; j < 4; ++j) {
        int n = nb + j;
        if (n < NN) {
            int p0 = out_ptr[n], p1 = out_ptr[n + 1];
            for (int p = p0; p < p1; ++p) {
                float4 a = oea[p];
                int slot = oslot[p];
                msg_out[((long)slot << 5) + o] =
                    ya[j][4] + a.x * ya[j][0] + a.y * ya[j][1]
                             + a.z * ya[j][2] + a.w * ya[j][3];
            }
        }
    }
}

// Fused mean-pool + classifier: one 64-thread block per graph (sorted batch,
// binary-search range, shuffle reduction).
__global__ __launch_bounds__(64) void k_pool_final(
    const float* __restrict__ feat, const int* __restrict__ batch,
    const float* __restrict__ w, const float* __restrict__ b,
    float* __restrict__ out) {
    int g = blockIdx.x;
    int t = threadIdx.x;
    int o = t & 31, h = t >> 5;
    int lo = 0, hi = NN;
    while (lo < hi) { int mid = (lo + hi) >> 1; if (batch[mid] < g) lo = mid + 1; else hi = mid; }
    int start = lo;
    hi = NN;
    while (lo < hi) { int mid = (lo + hi) >> 1; if (batch[mid] <= g) lo = mid + 1; else hi = mid; }
    int end = lo;
    float acc = 0.f;
    for (int n = start + h; n < end; n += 2) acc += feat[(long)n * 32 + o];
    acc += __shfl_xor(acc, 32, 64);
    float p = acc / fmaxf((float)(end - start), 1.f);
    float l0 = p * w[o], l1 = p * w[32 + o];
#pragma unroll
    for (int s = 16; s >= 1; s >>= 1) {
        l0 += __shfl_xor(l0, s, 64);
        l1 += __shfl_xor(l1, s, 64);
    }
    if (t == 0) {
        l0 += b[0]; l1 += b[1];
        float mx = fmaxf(l0, l1);
        float lse = mx + logf(__expf(l0 - mx) + __expf(l1 - mx));
        out[g * 2 + 0] = l0 - lse;
        out[g * 2 + 1] = l1 - lse;
    }
}

extern "C" void kernel_launch(void* const* d_in, const int* in_sizes, int n_in,
                              void* d_out, int out_size, void* d_ws, size_t ws_size,
                              hipStream_t stream) {
    const float* x        = (const float*)d_in[0];
    const float* edge_attr= (const float*)d_in[1];
    const float* lin0_w   = (const float*)d_in[2];
    const float* lin0_b   = (const float*)d_in[3];
    const float* nn_w     = (const float*)d_in[4];
    const float* nn_b     = (const float*)d_in[5];
    const float* root_w   = (const float*)d_in[6];
    const float* conv_b   = (const float*)d_in[7];
    const float* gru_wi   = (const float*)d_in[8];
    const float* gru_wh   = (const float*)d_in[9];
    const float* gru_bi   = (const float*)d_in[10];
    const float* gru_bh   = (const float*)d_in[11];
    const float* lin1_w   = (const float*)d_in[12];
    const float* lin1_b   = (const float*)d_in[13];
    const int*   edge_idx = (const int*)d_in[14];
    const int*   batch    = (const int*)d_in[15];
    float* out = (float*)d_out;

    float* ws     = (float*)d_ws;
    float* feat   = ws;                        // N*32 f
    float* Wre    = feat + (long)NN * 32;      // 5120 f
    float* WyT    = Wre + 5120;                // 5120 f
    float* wiT    = WyT + 5120;                // 3072 f
    float* whT    = wiT + 3072;                // 3072 f
    int*   cnt    = (int*)(whT + 3072);        // 2*NN i
    int*   tmp    = cnt + 2 * NN;              // 2*NN i
    int*   bsum   = tmp + 2 * NN;              // 512 i
    int*   row_ptr= bsum + 512;                // NN+1 i
    int*   cursor = row_ptr + NN + 1;          // NN i
    int*   out_ptr= cursor + NN;               // NN+1 i
    int*   cursor2= out_ptr + NN + 1;          // NN i
    int*   esrc   = cursor2 + NN;              // EE i
    int*   oslot  = esrc + EE;                 // EE i
    size_t off = ((size_t)((char*)(oslot + EE) - (char*)d_ws) + 15) & ~(size_t)15;
    float4* eea  = (float4*)((char*)d_ws + off);           // EE float4
    float4* oea  = eea + EE;                               // EE float4
    unsigned short* yb = (unsigned short*)(oea + EE);      // N*160 bf16
    float* msgA  = (float*)(yb + (long)NN * 160);          // E*32 f
    float* msgB  = msgA + (long)EE * 32;                   // E*32 f
    // total ~= 54 MB (ws is 256 MB)

    hipMemsetAsync(cnt, 0, 2 * NN * sizeof(int), stream);

    k_prep<<<64, 256, 0, stream>>>(nn_w, nn_b, gru_wi, gru_wh, Wre, WyT, wiT, whT);
    k_init<<<(NN * 32 + 255) / 256, 256, 0, stream>>>(x, lin0_w, lin0_b, feat);

    // CSR + CSC build (iteration-invariant)
    k_hist<<<(EE + 255) / 256, 256, 0, stream>>>(edge_idx, cnt);
    k_scan1<<<NB2, 256, 0, stream>>>(cnt, tmp, bsum);
    k_scan2<<<1, 512, 0, stream>>>(bsum);
    k_scan3<<<NB2, 256, 0, stream>>>(cnt, tmp, bsum, row_ptr, cursor, out_ptr, cursor2);
    k_scatter<<<(EE + 255) / 256, 256, 0, stream>>>(edge_idx, edge_attr, cursor, cursor2,
                                                    esrc, eea, oslot, oea);

    // Prologue: initial y + initial msg
    dim3 gy((NN + 63) / 64, 4);
    k_y<<<gy, 256, 0, stream>>>(feat, Wre, yb);
    k_msg<<<(EE * 32 + 255) / 256, 256, 0, stream>>>(yb, esrc, eea, msgA);

    // 3 fused iterations; msg ping-pongs A->B->A
    k_conv_update<<<(NN + 31) / 32, 256, 0, stream>>>(msgA, row_ptr, root_w, conv_b,
                                                      wiT, whT, gru_bi, gru_bh, WyT,
                                                      out_ptr, oslot, oea,
                                                      feat, msgB, 1);
    k_conv_update<<<(NN + 31) / 32, 256, 0, stream>>>(msgB, row_ptr, root_w, conv_b,
                                                      wiT, whT, gru_bi, gru_bh, WyT,
                                                      out_ptr, oslot, oea,
                                                      feat, msgA, 1);
    k_conv_update<<<(NN + 31) / 32, 256, 0, stream>>>(msgA, row_ptr, root_w, conv_b,
                                                      wiT, whT, gru_bi, gru_bh, WyT,
                                                      out_ptr, oslot, oea,
                                                      feat, msgB, 0);

    k_pool_final<<<GG, 64, 0, stream>>>(feat, batch, lin1_w, lin1_b, out);
}

// Round 12
// 273.405 us; speedup vs baseline: 1.6207x; 1.0716x over previous
//
#include <hip/hip_runtime.h>
#include <hip/hip_bf16.h>

// Problem constants (from reference)
#define NN 50000
#define EE 100000
#define GG 2048
#define NB2 391   // ceil(2*NN/256) for the dual (dst|src) scan

typedef float v2f __attribute__((ext_vector_type(2)));
__device__ __forceinline__ v2f fma2(v2f a, float b, v2f c) {
    return __builtin_elementwise_fma(a, (v2f){b, b}, c);
}

__device__ __forceinline__ float b2f(unsigned short u) {
    union { unsigned int i; float f; } x; x.i = (unsigned int)u << 16; return x.f;
}
__device__ __forceinline__ unsigned short f2b(float f) {
    union { float f; unsigned int i; } x; x.f = f;
    unsigned int b = x.i + (0x7FFFu + ((x.i >> 16) & 1u));   // RNE
    return (unsigned short)(b >> 16);
}

// Fused setup: blocks [0,6249] init feat; [6250,6277] build weight tables;
// [6278,6668] degree histogram.
__global__ __launch_bounds__(256) void k_setup(
    const float* __restrict__ x, const float* __restrict__ lw,
    const float* __restrict__ lb, const float* __restrict__ nnw,
    const float* __restrict__ nnb, const float* __restrict__ rootw,
    const float* __restrict__ wi, const float* __restrict__ wh,
    const int* __restrict__ ei, float* __restrict__ feat,
    float* __restrict__ Wre, float4* __restrict__ rw4,
    float4* __restrict__ wi4, int* __restrict__ cnt) {
    int blk = blockIdx.x;
    int t = threadIdx.x;
    if (blk < 6250) {
        int idx = blk * 256 + t;
        if (idx >= NN * 32) return;
        int n = idx >> 5, o = idx & 31;
        const float* xr = x + n * 11;
        const float* wr = lw + o * 11;
        float acc = lb[o];
#pragma unroll
        for (int i = 0; i < 11; ++i) acc += xr[i] * wr[i];
        feat[idx] = fmaxf(acc, 0.f);
    } else if (blk < 6278) {
        int idx = (blk - 6250) * 256 + t;
        if (idx < 5120) {
            int c = idx >> 5, i = idx & 31;
            float v;
            if (c < 128) v = nnw[((i << 5) + (c & 31)) * 4 + (c >> 5)];
            else         v = nnb[(i << 5) + (c - 128)];
            Wre[idx] = v;
        } else if (idx < 6144) {
            int j = idx - 5120;
            int k = j >> 5, o = j & 31;
            rw4[j] = make_float4(rootw[k * 32 + o], wh[o * 32 + k],
                                 wh[(32 + o) * 32 + k], wh[(64 + o) * 32 + k]);
        } else if (idx < 7168) {
            int j = idx - 6144;
            int k = j >> 5, o = j & 31;
            wi4[j] = make_float4(wi[o * 32 + k], wi[(32 + o) * 32 + k],
                                 wi[(64 + o) * 32 + k], 0.f);
        }
    } else {
        int e = (blk - 6278) * 256 + t;
        if (e >= EE) return;
        atomicAdd(&cnt[ei[EE + e]], 1);
        atomicAdd(&cnt[NN + ei[e]], 1);
    }
}

__global__ __launch_bounds__(256) void k_scan1(const int* __restrict__ cnt,
                                               int* __restrict__ tmp,
                                               int* __restrict__ bsum) {
    __shared__ int sd[256];
    int t = threadIdx.x;
    int i = blockIdx.x * 256 + t;
    int v = (i < 2 * NN) ? cnt[i] : 0;
    sd[t] = v;
    __syncthreads();
#pragma unroll
    for (int off = 1; off < 256; off <<= 1) {
        int x = (t >= off) ? sd[t - off] : 0;
        __syncthreads();
        sd[t] += x;
        __syncthreads();
    }
    if (i < 2 * NN) tmp[i] = sd[t];
    if (t == 255) bsum[blockIdx.x] = sd[255];
}

__global__ __launch_bounds__(512) void k_scan2(int* __restrict__ bsum) {
    __shared__ int sd[512];
    int t = threadIdx.x;
    int v = (t < NB2) ? bsum[t] : 0;
    sd[t] = v;
    __syncthreads();
#pragma unroll
    for (int off = 1; off < 512; off <<= 1) {
        int x = (t >= off) ? sd[t - off] : 0;
        __syncthreads();
        sd[t] += x;
        __syncthreads();
    }
    if (t < NB2) bsum[t] = sd[t];
}

__global__ void k_scan3(const int* __restrict__ cnt, const int* __restrict__ tmp,
                        const int* __restrict__ bsum, int* __restrict__ row_ptr,
                        int* __restrict__ cursor, int* __restrict__ out_ptr,
                        int* __restrict__ cursor2) {
    int i = blockIdx.x * blockDim.x + threadIdx.x;
    if (i >= 2 * NN) return;
    int base = (blockIdx.x > 0) ? bsum[blockIdx.x - 1] : 0;
    int excl = base + tmp[i] - cnt[i];
    if (i < NN) {
        row_ptr[i] = excl;
        cursor[i] = excl;
        if (i == 0) row_ptr[NN] = EE;
    } else {
        int j = i - NN;
        out_ptr[j] = excl - EE;
        cursor2[j] = excl - EE;
        if (j == 0) out_ptr[NN] = EE;
    }
}

// Fused: blocks [0,390] scatter edges into CSR/CSC; blocks [391, 391+3127]
// compute the initial y table (on k_setup's feat).
__global__ __launch_bounds__(256) void k_scatter_y(
    const int* __restrict__ ei, const float* __restrict__ ea,
    int* __restrict__ cursor, int* __restrict__ cursor2,
    int* __restrict__ esrc, float4* __restrict__ eea,
    int* __restrict__ oslot, float4* __restrict__ oea,
    const float* __restrict__ feat, const float* __restrict__ Wre,
    unsigned short* __restrict__ yb) {
    int blk = blockIdx.x;
    if (blk < 391) {
        int e = blk * 256 + threadIdx.x;
        if (e >= EE) return;
        int s = ei[e], d = ei[EE + e];
        float4 a = make_float4(ea[e * 4 + 0], ea[e * 4 + 1], ea[e * 4 + 2], ea[e * 4 + 3]);
        int slot = atomicAdd(&cursor[d], 1);
        esrc[slot] = s;
        eea[slot] = a;
        int pos = atomicAdd(&cursor2[s], 1);
        oslot[pos] = slot;
        oea[pos] = a;
        return;
    }
    int by = blk - 391;
    int bx = by % 782, q = by / 782;
    int lane = threadIdx.x & 63;
    int wv = __builtin_amdgcn_readfirstlane(threadIdx.x >> 6);
    int n = bx * 64 + lane;
    if (n >= NN) return;
    int c0 = q * 40 + wv * 10;
    float fr[32];
    const float4* f4 = (const float4*)(feat + (long)n * 32);
#pragma unroll
    for (int qq = 0; qq < 8; ++qq) {
        float4 v = f4[qq];
        fr[4 * qq + 0] = v.x; fr[4 * qq + 1] = v.y;
        fr[4 * qq + 2] = v.z; fr[4 * qq + 3] = v.w;
    }
    float acc[10];
#pragma unroll
    for (int cc = 0; cc < 10; ++cc) {
        const float* w = Wre + (c0 + cc) * 32;   // uniform address -> s_load
        float a = 0.f;
#pragma unroll
        for (int i = 0; i < 32; ++i) a += fr[i] * w[i];
        acc[cc] = a;
    }
    unsigned short* yr = yb + (long)n * 160 + c0;
#pragma unroll
    for (int qq = 0; qq < 5; ++qq) {
        unsigned int wlo = f2b(acc[2 * qq]);
        unsigned int whi = f2b(acc[2 * qq + 1]);
        ((unsigned int*)yr)[qq] = wlo | (whi << 16);
    }
}

// Prologue edge-parallel message (iteration 0 only).
__global__ __launch_bounds__(256) void k_msg(
    const unsigned short* __restrict__ yb, const int* __restrict__ esrc,
    const float4* __restrict__ eea, float* __restrict__ msg) {
    int idx = blockIdx.x * 256 + threadIdx.x;
    if (idx >= EE * 32) return;
    int slot = idx >> 5, o = idx & 31;
    int s = esrc[slot];
    float4 a = eea[slot];
    const unsigned short* yr = yb + (long)s * 160;
    float y0 = b2f(yr[o]);
    float y1 = b2f(yr[32 + o]);
    float y2 = b2f(yr[64 + o]);
    float y3 = b2f(yr[96 + o]);
    float y4 = b2f(yr[128 + o]);
    msg[idx] = y4 + a.x * y0 + a.y * y1 + a.z * y2 + a.w * y3;
}

// Fused iteration kernel: msg-sum + (root|GRU-h) + GRU-i + gates + next msg.
// 32-lane group = 4 nodes; transposed LDS tiles -> broadcast ds_read_b128;
// float4-packed weights; float2 paired accumulators (v_pk_fma where avail).
__global__ __launch_bounds__(256) void k_conv_update(
    const float* __restrict__ msg_in, const int* __restrict__ row_ptr,
    const float4* __restrict__ rw4, const float* __restrict__ convb,
    const float4* __restrict__ wi4, const float* __restrict__ bi,
    const float* __restrict__ bh, const float4* __restrict__ nnw4,
    const float* __restrict__ nnb, const int* __restrict__ out_ptr,
    const int* __restrict__ oslot, const float4* __restrict__ oea,
    float* __restrict__ feat, float* __restrict__ msg_out, int write_msg) {
    __shared__ float fsT[32][36];   // [dim][node], pad 36 for bank spread
    __shared__ float msT[32][36];
    int t = threadIdx.x;
    int g = t >> 5, o = t & 31;
    int gc = g * 4;
    int nb = blockIdx.x * 32 + gc;
    float f[4], m[4];
    float cb = convb[o];
#pragma unroll
    for (int j = 0; j < 4; ++j) {
        int n = nb + j;
        bool v = (n < NN);
        f[j] = v ? feat[n * 32 + o] : 0.f;
        m[j] = cb;
        if (v) {
            int e0 = row_ptr[n], e1 = row_ptr[n + 1];
            for (int e = e0; e < e1; ++e)
                m[j] += msg_in[(e << 5) + o];
        }
    }
    *(float4*)&fsT[o][gc] = make_float4(f[0], f[1], f[2], f[3]);
    __syncthreads();

    // phase ab: m_pre += f@root ; gh = f@wh  (rw4 = root|whr|whz|whn)
    float bhr = bh[o], bhz = bh[32 + o], bhn = bh[64 + o];
    v2f m01 = {m[0], m[1]}, m23 = {m[2], m[3]};
    v2f ghr01 = {bhr, bhr}, ghr23 = {bhr, bhr};
    v2f ghz01 = {bhz, bhz}, ghz23 = {bhz, bhz};
    v2f ghn01 = {bhn, bhn}, ghn23 = {bhn, bhn};
#pragma unroll 4
    for (int i = 0; i < 32; ++i) {
        float4 w = rw4[i * 32 + o];
        float4 fv = *(const float4*)&fsT[i][gc];   // broadcast read
        v2f f01 = {fv.x, fv.y}, f23 = {fv.z, fv.w};
        m01 = fma2(f01, w.x, m01);   m23 = fma2(f23, w.x, m23);
        ghr01 = fma2(f01, w.y, ghr01); ghr23 = fma2(f23, w.y, ghr23);
        ghz01 = fma2(f01, w.z, ghz01); ghz23 = fma2(f23, w.z, ghz23);
        ghn01 = fma2(f01, w.w, ghn01); ghn23 = fma2(f23, w.w, ghn23);
    }
    float mm0 = fmaxf(m01.x, 0.f), mm1 = fmaxf(m01.y, 0.f);
    float mm2 = fmaxf(m23.x, 0.f), mm3 = fmaxf(m23.y, 0.f);
    *(float4*)&msT[o][gc] = make_float4(mm0, mm1, mm2, mm3);
    __syncthreads();

    // phase c: gi = m@wi
    float bir = bi[o], biz = bi[32 + o], bin_ = bi[64 + o];
    v2f gir01 = {bir, bir}, gir23 = {bir, bir};
    v2f giz01 = {biz, biz}, giz23 = {biz, biz};
    v2f gin01 = {bin_, bin_}, gin23 = {bin_, bin_};
#pragma unroll 4
    for (int k = 0; k < 32; ++k) {
        float4 w = wi4[k * 32 + o];
        float4 mv = *(const float4*)&msT[k][gc];
        v2f p01 = {mv.x, mv.y}, p23 = {mv.z, mv.w};
        gir01 = fma2(p01, w.x, gir01); gir23 = fma2(p23, w.x, gir23);
        giz01 = fma2(p01, w.y, giz01); giz23 = fma2(p23, w.y, giz23);
        gin01 = fma2(p01, w.z, gin01); gin23 = fma2(p23, w.z, gin23);
    }
    float girA[4] = {gir01.x, gir01.y, gir23.x, gir23.y};
    float gizA[4] = {giz01.x, giz01.y, giz23.x, giz23.y};
    float ginA[4] = {gin01.x, gin01.y, gin23.x, gin23.y};
    float ghrA[4] = {ghr01.x, ghr01.y, ghr23.x, ghr23.y};
    float ghzA[4] = {ghz01.x, ghz01.y, ghz23.x, ghz23.y};
    float ghnA[4] = {ghn01.x, ghn01.y, ghn23.x, ghn23.y};
    float fn[4];
#pragma unroll
    for (int j = 0; j < 4; ++j) {
        int n = nb + j;
        float r = 1.f / (1.f + __expf(-(girA[j] + ghrA[j])));
        float z = 1.f / (1.f + __expf(-(gizA[j] + ghzA[j])));
        float nt = tanhf(ginA[j] + r * ghnA[j]);
        fn[j] = (1.f - z) * nt + z * f[j];
        if (n < NN) feat[n * 32 + o] = fn[j];
    }
    if (!write_msg) return;

    // ya phase: reuse fsT rows (same-wave write->read, lgkmcnt-ordered)
    *(float4*)&fsT[o][gc] = make_float4(fn[0], fn[1], fn[2], fn[3]);
    v2f y0_01 = {0.f, 0.f}, y0_23 = {0.f, 0.f};
    v2f y1_01 = {0.f, 0.f}, y1_23 = {0.f, 0.f};
    v2f y2_01 = {0.f, 0.f}, y2_23 = {0.f, 0.f};
    v2f y3_01 = {0.f, 0.f}, y3_23 = {0.f, 0.f};
    v2f y4_01 = {0.f, 0.f}, y4_23 = {0.f, 0.f};
#pragma unroll 4
    for (int i = 0; i < 32; ++i) {
        float4 w = nnw4[i * 32 + o];      // nn_w row (i*32+o): q=0..3
        float w1 = nnb[i * 32 + o];
        float4 fv = *(const float4*)&fsT[i][gc];
        v2f f01 = {fv.x, fv.y}, f23 = {fv.z, fv.w};
        y0_01 = fma2(f01, w.x, y0_01); y0_23 = fma2(f23, w.x, y0_23);
        y1_01 = fma2(f01, w.y, y1_01); y1_23 = fma2(f23, w.y, y1_23);
        y2_01 = fma2(f01, w.z, y2_01); y2_23 = fma2(f23, w.z, y2_23);
        y3_01 = fma2(f01, w.w, y3_01); y3_23 = fma2(f23, w.w, y3_23);
        y4_01 = fma2(f01, w1, y4_01);  y4_23 = fma2(f23, w1, y4_23);
    }
    float ya0[4] = {y0_01.x, y0_01.y, y0_23.x, y0_23.y};
    float ya1[4] = {y1_01.x, y1_01.y, y1_23.x, y1_23.y};
    float ya2[4] = {y2_01.x, y2_01.y, y2_23.x, y2_23.y};
    float ya3[4] = {y3_01.x, y3_01.y, y3_23.x, y3_23.y};
    float ya4[4] = {y4_01.x, y4_01.y, y4_23.x, y4_23.y};
#pragma unroll
    for (int j = 0; j < 4; ++j) {
        int n = nb + j;
        if (n < NN) {
            int p0 = out_ptr[n], p1 = out_ptr[n + 1];
            for (int p = p0; p < p1; ++p) {
                float4 a = oea[p];
                int slot = oslot[p];
                msg_out[(slot << 5) + o] =
                    ya4[j] + a.x * ya0[j] + a.y * ya1[j]
                           + a.z * ya2[j] + a.w * ya3[j];
            }
        }
    }
}

// Fused mean-pool + classifier
__global__ __launch_bounds__(64) void k_pool_final(
    const float* __restrict__ feat, const int* __restrict__ batch,
    const float* __restrict__ w, const float* __restrict__ b,
    float* __restrict__ out) {
    int g = blockIdx.x;
    int t = threadIdx.x;
    int o = t & 31, h = t >> 5;
    int lo = 0, hi = NN;
    while (lo < hi) { int mid = (lo + hi) >> 1; if (batch[mid] < g) lo = mid + 1; else hi = mid; }
    int start = lo;
    hi = NN;
    while (lo < hi) { int mid = (lo + hi) >> 1; if (batch[mid] <= g) lo = mid + 1; else hi = mid; }
    int end = lo;
    float acc = 0.f;
    for (int n = start + h; n < end; n += 2) acc += feat[(long)n * 32 + o];
    acc += __shfl_xor(acc, 32, 64);
    float p = acc / fmaxf((float)(end - start), 1.f);
    float l0 = p * w[o], l1 = p * w[32 + o];
#pragma unroll
    for (int s = 16; s >= 1; s >>= 1) {
        l0 += __shfl_xor(l0, s, 64);
        l1 += __shfl_xor(l1, s, 64);
    }
    if (t == 0) {
        l0 += b[0]; l1 += b[1];
        float mx = fmaxf(l0, l1);
        float lse = mx + logf(__expf(l0 - mx) + __expf(l1 - mx));
        out[g * 2 + 0] = l0 - lse;
        out[g * 2 + 1] = l1 - lse;
    }
}

extern "C" void kernel_launch(void* const* d_in, const int* in_sizes, int n_in,
                              void* d_out, int out_size, void* d_ws, size_t ws_size,
                              hipStream_t stream) {
    const float* x        = (const float*)d_in[0];
    const float* edge_attr= (const float*)d_in[1];
    const float* lin0_w   = (const float*)d_in[2];
    const float* lin0_b   = (const float*)d_in[3];
    const float* nn_w     = (const float*)d_in[4];
    const float* nn_b     = (const float*)d_in[5];
    const float* root_w   = (const float*)d_in[6];
    const float* conv_b   = (const float*)d_in[7];
    const float* gru_wi   = (const float*)d_in[8];
    const float* gru_wh   = (const float*)d_in[9];
    const float* gru_bi   = (const float*)d_in[10];
    const float* gru_bh   = (const float*)d_in[11];
    const float* lin1_w   = (const float*)d_in[12];
    const float* lin1_b   = (const float*)d_in[13];
    const int*   edge_idx = (const int*)d_in[14];
    const int*   batch    = (const int*)d_in[15];
    float* out = (float*)d_out;

    // layout: float4 tables first (16B alignment guaranteed at ws base)
    float4* rw4   = (float4*)d_ws;             // 1024
    float4* wi4   = rw4 + 1024;                // 1024
    float4* eea   = wi4 + 1024;                // EE
    float4* oea   = eea + EE;                  // EE
    float*  feat  = (float*)(oea + EE);        // N*32
    float*  Wre   = feat + (long)NN * 32;      // 5120
    int*    cnt   = (int*)(Wre + 5120);        // 2N
    int*    tmp   = cnt + 2 * NN;              // 2N
    int*    bsum  = tmp + 2 * NN;              // 512
    int*    row_ptr = bsum + 512;              // N+1
    int*    cursor  = row_ptr + NN + 1;        // N
    int*    out_ptr = cursor + NN;             // N+1
    int*    cursor2 = out_ptr + NN + 1;        // N
    int*    esrc  = cursor2 + NN;              // EE
    int*    oslot = esrc + EE;                 // EE
    unsigned short* yb = (unsigned short*)(oslot + EE);  // N*160
    float*  msgA  = (float*)(yb + (long)NN * 160);       // E*32
    float*  msgB  = msgA + (long)EE * 32;                // E*32
    const float4* nnw4 = (const float4*)nn_w;  // [1024] rows of 4

    hipMemsetAsync(cnt, 0, 2 * NN * sizeof(int), stream);

    // init + weight tables + histogram (block-partitioned)
    k_setup<<<6250 + 28 + 391, 256, 0, stream>>>(x, lin0_w, lin0_b, nn_w, nn_b,
                                                 root_w, gru_wi, gru_wh, edge_idx,
                                                 feat, Wre, rw4, wi4, cnt);

    k_scan1<<<NB2, 256, 0, stream>>>(cnt, tmp, bsum);
    k_scan2<<<1, 512, 0, stream>>>(bsum);
    k_scan3<<<NB2, 256, 0, stream>>>(cnt, tmp, bsum, row_ptr, cursor, out_ptr, cursor2);

    // scatter + initial y (block-partitioned)
    k_scatter_y<<<391 + 782 * 4, 256, 0, stream>>>(edge_idx, edge_attr, cursor, cursor2,
                                                   esrc, eea, oslot, oea, feat, Wre, yb);
    k_msg<<<(EE * 32 + 255) / 256, 256, 0, stream>>>(yb, esrc, eea, msgA);

    // 3 fused iterations; msg ping-pongs A->B->A
    k_conv_update<<<(NN + 31) / 32, 256, 0, stream>>>(msgA, row_ptr, rw4, conv_b, wi4,
                                                      gru_bi, gru_bh, nnw4, nn_b,
                                                      out_ptr, oslot, oea,
                                                      feat, msgB, 1);
    k_conv_update<<<(NN + 31) / 32, 256, 0, stream>>>(msgB, row_ptr, rw4, conv_b, wi4,
                                                      gru_bi, gru_bh, nnw4, nn_b,
                                                      out_ptr, oslot, oea,
                                                      feat, msgA, 1);
    k_conv_update<<<(NN + 31) / 32, 256, 0, stream>>>(msgA, row_ptr, rw4, conv_b, wi4,
                                                      gru_bi, gru_bh, nnw4, nn_b,
                                                      out_ptr, oslot, oea,
                                                      feat, msgB, 0);

    k_pool_final<<<GG, 64, 0, stream>>>(feat, batch, lin1_w, lin1_b, out);
}

// Round 13
// 266.354 us; speedup vs baseline: 1.6636x; 1.0265x over previous
//
#include <hip/hip_runtime.h>
#include <hip/hip_bf16.h>

// Problem constants (from reference)
#define NN 50000
#define EE 100000
#define GG 2048
#define NB2 391   // ceil(2*NN/256) for the dual (dst|src) scan

typedef float v2f __attribute__((ext_vector_type(2)));
__device__ __forceinline__ v2f fma2(v2f a, float b, v2f c) {
    return __builtin_elementwise_fma(a, (v2f){b, b}, c);
}

__device__ __forceinline__ float b2f(unsigned short u) {
    union { unsigned int i; float f; } x; x.i = (unsigned int)u << 16; return x.f;
}
__device__ __forceinline__ unsigned short f2b(float f) {
    union { float f; unsigned int i; } x; x.f = f;
    unsigned int b = x.i + (0x7FFFu + ((x.i >> 16) & 1u));   // RNE
    return (unsigned short)(b >> 16);
}

// Fused setup: blocks [0,6249] init feat; [6250,6277] build weight tables;
// [6278,6668] degree histogram.
__global__ __launch_bounds__(256) void k_setup(
    const float* __restrict__ x, const float* __restrict__ lw,
    const float* __restrict__ lb, const float* __restrict__ nnw,
    const float* __restrict__ nnb, const float* __restrict__ rootw,
    const float* __restrict__ wi, const float* __restrict__ wh,
    const int* __restrict__ ei, float* __restrict__ feat,
    float* __restrict__ Wre, float4* __restrict__ rw4,
    float4* __restrict__ wi4, int* __restrict__ cnt) {
    int blk = blockIdx.x;
    int t = threadIdx.x;
    if (blk < 6250) {
        int idx = blk * 256 + t;
        if (idx >= NN * 32) return;
        int n = idx >> 5, o = idx & 31;
        const float* xr = x + n * 11;
        const float* wr = lw + o * 11;
        float acc = lb[o];
#pragma unroll
        for (int i = 0; i < 11; ++i) acc += xr[i] * wr[i];
        feat[idx] = fmaxf(acc, 0.f);
    } else if (blk < 6278) {
        int idx = (blk - 6250) * 256 + t;
        if (idx < 5120) {
            int c = idx >> 5, i = idx & 31;
            float v;
            if (c < 128) v = nnw[((i << 5) + (c & 31)) * 4 + (c >> 5)];
            else         v = nnb[(i << 5) + (c - 128)];
            Wre[idx] = v;
        } else if (idx < 6144) {
            int j = idx - 5120;
            int k = j >> 5, o = j & 31;
            rw4[j] = make_float4(rootw[k * 32 + o], wh[o * 32 + k],
                                 wh[(32 + o) * 32 + k], wh[(64 + o) * 32 + k]);
        } else if (idx < 7168) {
            int j = idx - 6144;
            int k = j >> 5, o = j & 31;
            wi4[j] = make_float4(wi[o * 32 + k], wi[(32 + o) * 32 + k],
                                 wi[(64 + o) * 32 + k], 0.f);
        }
    } else {
        int e = (blk - 6278) * 256 + t;
        if (e >= EE) return;
        atomicAdd(&cnt[ei[EE + e]], 1);
        atomicAdd(&cnt[NN + ei[e]], 1);
    }
}

__global__ __launch_bounds__(256) void k_scan1(const int* __restrict__ cnt,
                                               int* __restrict__ tmp,
                                               int* __restrict__ bsum) {
    __shared__ int sd[256];
    int t = threadIdx.x;
    int i = blockIdx.x * 256 + t;
    int v = (i < 2 * NN) ? cnt[i] : 0;
    sd[t] = v;
    __syncthreads();
#pragma unroll
    for (int off = 1; off < 256; off <<= 1) {
        int x = (t >= off) ? sd[t - off] : 0;
        __syncthreads();
        sd[t] += x;
        __syncthreads();
    }
    if (i < 2 * NN) tmp[i] = sd[t];
    if (t == 255) bsum[blockIdx.x] = sd[255];
}

__global__ __launch_bounds__(512) void k_scan2(int* __restrict__ bsum) {
    __shared__ int sd[512];
    int t = threadIdx.x;
    int v = (t < NB2) ? bsum[t] : 0;
    sd[t] = v;
    __syncthreads();
#pragma unroll
    for (int off = 1; off < 512; off <<= 1) {
        int x = (t >= off) ? sd[t - off] : 0;
        __syncthreads();
        sd[t] += x;
        __syncthreads();
    }
    if (t < NB2) bsum[t] = sd[t];
}

__global__ void k_scan3(const int* __restrict__ cnt, const int* __restrict__ tmp,
                        const int* __restrict__ bsum, int* __restrict__ row_ptr,
                        int* __restrict__ cursor, int* __restrict__ out_ptr,
                        int* __restrict__ cursor2) {
    int i = blockIdx.x * blockDim.x + threadIdx.x;
    if (i >= 2 * NN) return;
    int base = (blockIdx.x > 0) ? bsum[blockIdx.x - 1] : 0;
    int excl = base + tmp[i] - cnt[i];
    if (i < NN) {
        row_ptr[i] = excl;
        cursor[i] = excl;
        if (i == 0) row_ptr[NN] = EE;
    } else {
        int j = i - NN;
        out_ptr[j] = excl - EE;
        cursor2[j] = excl - EE;
        if (j == 0) out_ptr[NN] = EE;
    }
}

// Fused: blocks [0,390] scatter edges into CSR/CSC; blocks [391, 391+3127]
// compute the initial y table (on k_setup's feat).
__global__ __launch_bounds__(256) void k_scatter_y(
    const int* __restrict__ ei, const float* __restrict__ ea,
    int* __restrict__ cursor, int* __restrict__ cursor2,
    int* __restrict__ esrc, float4* __restrict__ eea,
    int* __restrict__ oslot, float4* __restrict__ oea,
    const float* __restrict__ feat, const float* __restrict__ Wre,
    unsigned short* __restrict__ yb) {
    int blk = blockIdx.x;
    if (blk < 391) {
        int e = blk * 256 + threadIdx.x;
        if (e >= EE) return;
        int s = ei[e], d = ei[EE + e];
        float4 a = make_float4(ea[e * 4 + 0], ea[e * 4 + 1], ea[e * 4 + 2], ea[e * 4 + 3]);
        int slot = atomicAdd(&cursor[d], 1);
        esrc[slot] = s;
        eea[slot] = a;
        int pos = atomicAdd(&cursor2[s], 1);
        oslot[pos] = slot;
        oea[pos] = a;
        return;
    }
    int by = blk - 391;
    int bx = by % 782, q = by / 782;
    int lane = threadIdx.x & 63;
    int wv = __builtin_amdgcn_readfirstlane(threadIdx.x >> 6);
    int n = bx * 64 + lane;
    if (n >= NN) return;
    int c0 = q * 40 + wv * 10;
    float fr[32];
    const float4* f4 = (const float4*)(feat + (long)n * 32);
#pragma unroll
    for (int qq = 0; qq < 8; ++qq) {
        float4 v = f4[qq];
        fr[4 * qq + 0] = v.x; fr[4 * qq + 1] = v.y;
        fr[4 * qq + 2] = v.z; fr[4 * qq + 3] = v.w;
    }
    float acc[10];
#pragma unroll
    for (int cc = 0; cc < 10; ++cc) {
        const float* w = Wre + (c0 + cc) * 32;   // uniform address -> s_load
        float a = 0.f;
#pragma unroll
        for (int i = 0; i < 32; ++i) a += fr[i] * w[i];
        acc[cc] = a;
    }
    unsigned short* yr = yb + (long)n * 160 + c0;
#pragma unroll
    for (int qq = 0; qq < 5; ++qq) {
        unsigned int wlo = f2b(acc[2 * qq]);
        unsigned int whi = f2b(acc[2 * qq + 1]);
        ((unsigned int*)yr)[qq] = wlo | (whi << 16);
    }
}

// Fused iteration kernel: msg-gather + (root|GRU-h) + GRU-i + gates + next msg.
// 32-lane group = 4 nodes; transposed LDS tiles -> broadcast ds_read_b128;
// float4-packed weights; float2 paired accumulators.
// gather_from_y: iter-1 gathers straight from the bf16 y table (no msg_in);
// otherwise gathers from bf16 msg_in. msg_out is bf16.
__global__ __launch_bounds__(256) void k_conv_update(
    const unsigned short* __restrict__ msg_in, const int* __restrict__ row_ptr,
    const float4* __restrict__ rw4, const float* __restrict__ convb,
    const float4* __restrict__ wi4, const float* __restrict__ bi,
    const float* __restrict__ bh, const float4* __restrict__ nnw4,
    const float* __restrict__ nnb, const int* __restrict__ out_ptr,
    const int* __restrict__ oslot, const float4* __restrict__ oea,
    const unsigned short* __restrict__ yb, const int* __restrict__ esrc,
    const float4* __restrict__ eea,
    float* __restrict__ feat, unsigned short* __restrict__ msg_out,
    int gather_from_y, int write_msg) {
    __shared__ float fsT[32][36];   // [dim][node], pad 36 for bank spread
    __shared__ float msT[32][36];
    int t = threadIdx.x;
    int g = t >> 5, o = t & 31;
    int gc = g * 4;
    int nb = blockIdx.x * 32 + gc;
    float f[4], m[4];
    float cb = convb[o];
#pragma unroll
    for (int j = 0; j < 4; ++j) {
        int n = nb + j;
        bool v = (n < NN);
        f[j] = v ? feat[n * 32 + o] : 0.f;
        m[j] = cb;
        if (v) {
            int e0 = row_ptr[n], e1 = row_ptr[n + 1];
            if (gather_from_y) {
                for (int e = e0; e < e1; ++e) {
                    int s = esrc[e];               // uniform across group
                    float4 a = eea[e];
                    const unsigned short* yr = yb + (long)s * 160;
                    float y0 = b2f(yr[o]);
                    float y1 = b2f(yr[32 + o]);
                    float y2 = b2f(yr[64 + o]);
                    float y3 = b2f(yr[96 + o]);
                    float y4 = b2f(yr[128 + o]);
                    m[j] += y4 + a.x * y0 + a.y * y1 + a.z * y2 + a.w * y3;
                }
            } else {
                for (int e = e0; e < e1; ++e)
                    m[j] += b2f(msg_in[(e << 5) + o]);
            }
        }
    }
    *(float4*)&fsT[o][gc] = make_float4(f[0], f[1], f[2], f[3]);
    __syncthreads();

    // phase ab: m_pre += f@root ; gh = f@wh  (rw4 = root|whr|whz|whn)
    float bhr = bh[o], bhz = bh[32 + o], bhn = bh[64 + o];
    v2f m01 = {m[0], m[1]}, m23 = {m[2], m[3]};
    v2f ghr01 = {bhr, bhr}, ghr23 = {bhr, bhr};
    v2f ghz01 = {bhz, bhz}, ghz23 = {bhz, bhz};
    v2f ghn01 = {bhn, bhn}, ghn23 = {bhn, bhn};
#pragma unroll 4
    for (int i = 0; i < 32; ++i) {
        float4 w = rw4[i * 32 + o];
        float4 fv = *(const float4*)&fsT[i][gc];   // broadcast read
        v2f f01 = {fv.x, fv.y}, f23 = {fv.z, fv.w};
        m01 = fma2(f01, w.x, m01);   m23 = fma2(f23, w.x, m23);
        ghr01 = fma2(f01, w.y, ghr01); ghr23 = fma2(f23, w.y, ghr23);
        ghz01 = fma2(f01, w.z, ghz01); ghz23 = fma2(f23, w.z, ghz23);
        ghn01 = fma2(f01, w.w, ghn01); ghn23 = fma2(f23, w.w, ghn23);
    }
    float mm0 = fmaxf(m01.x, 0.f), mm1 = fmaxf(m01.y, 0.f);
    float mm2 = fmaxf(m23.x, 0.f), mm3 = fmaxf(m23.y, 0.f);
    *(float4*)&msT[o][gc] = make_float4(mm0, mm1, mm2, mm3);
    __syncthreads();

    // phase c: gi = m@wi
    float bir = bi[o], biz = bi[32 + o], bin_ = bi[64 + o];
    v2f gir01 = {bir, bir}, gir23 = {bir, bir};
    v2f giz01 = {biz, biz}, giz23 = {biz, biz};
    v2f gin01 = {bin_, bin_}, gin23 = {bin_, bin_};
#pragma unroll 4
    for (int k = 0; k < 32; ++k) {
        float4 w = wi4[k * 32 + o];
        float4 mv = *(const float4*)&msT[k][gc];
        v2f p01 = {mv.x, mv.y}, p23 = {mv.z, mv.w};
        gir01 = fma2(p01, w.x, gir01); gir23 = fma2(p23, w.x, gir23);
        giz01 = fma2(p01, w.y, giz01); giz23 = fma2(p23, w.y, giz23);
        gin01 = fma2(p01, w.z, gin01); gin23 = fma2(p23, w.z, gin23);
    }
    float girA[4] = {gir01.x, gir01.y, gir23.x, gir23.y};
    float gizA[4] = {giz01.x, giz01.y, giz23.x, giz23.y};
    float ginA[4] = {gin01.x, gin01.y, gin23.x, gin23.y};
    float ghrA[4] = {ghr01.x, ghr01.y, ghr23.x, ghr23.y};
    float ghzA[4] = {ghz01.x, ghz01.y, ghz23.x, ghz23.y};
    float ghnA[4] = {ghn01.x, ghn01.y, ghn23.x, ghn23.y};
    float fn[4];
#pragma unroll
    for (int j = 0; j < 4; ++j) {
        int n = nb + j;
        float r = 1.f / (1.f + __expf(-(girA[j] + ghrA[j])));
        float z = 1.f / (1.f + __expf(-(gizA[j] + ghzA[j])));
        float nt = tanhf(ginA[j] + r * ghnA[j]);
        fn[j] = (1.f - z) * nt + z * f[j];
        if (n < NN) feat[n * 32 + o] = fn[j];
    }
    if (!write_msg) return;

    // ya phase: reuse fsT rows (same-wave write->read, lgkmcnt-ordered)
    *(float4*)&fsT[o][gc] = make_float4(fn[0], fn[1], fn[2], fn[3]);
    v2f y0_01 = {0.f, 0.f}, y0_23 = {0.f, 0.f};
    v2f y1_01 = {0.f, 0.f}, y1_23 = {0.f, 0.f};
    v2f y2_01 = {0.f, 0.f}, y2_23 = {0.f, 0.f};
    v2f y3_01 = {0.f, 0.f}, y3_23 = {0.f, 0.f};
    v2f y4_01 = {0.f, 0.f}, y4_23 = {0.f, 0.f};
#pragma unroll 4
    for (int i = 0; i < 32; ++i) {
        float4 w = nnw4[i * 32 + o];      // nn_w row (i*32+o): q=0..3
        float w1 = nnb[i * 32 + o];
        float4 fv = *(const float4*)&fsT[i][gc];
        v2f f01 = {fv.x, fv.y}, f23 = {fv.z, fv.w};
        y0_01 = fma2(f01, w.x, y0_01); y0_23 = fma2(f23, w.x, y0_23);
        y1_01 = fma2(f01, w.y, y1_01); y1_23 = fma2(f23, w.y, y1_23);
        y2_01 = fma2(f01, w.z, y2_01); y2_23 = fma2(f23, w.z, y2_23);
        y3_01 = fma2(f01, w.w, y3_01); y3_23 = fma2(f23, w.w, y3_23);
        y4_01 = fma2(f01, w1, y4_01);  y4_23 = fma2(f23, w1, y4_23);
    }
    float ya0[4] = {y0_01.x, y0_01.y, y0_23.x, y0_23.y};
    float ya1[4] = {y1_01.x, y1_01.y, y1_23.x, y1_23.y};
    float ya2[4] = {y2_01.x, y2_01.y, y2_23.x, y2_23.y};
    float ya3[4] = {y3_01.x, y3_01.y, y3_23.x, y3_23.y};
    float ya4[4] = {y4_01.x, y4_01.y, y4_23.x, y4_23.y};
#pragma unroll
    for (int j = 0; j < 4; ++j) {
        int n = nb + j;
        if (n < NN) {
            int p0 = out_ptr[n], p1 = out_ptr[n + 1];
            for (int p = p0; p < p1; ++p) {
                float4 a = oea[p];
                int slot = oslot[p];
                msg_out[(slot << 5) + o] =
                    f2b(ya4[j] + a.x * ya0[j] + a.y * ya1[j]
                               + a.z * ya2[j] + a.w * ya3[j]);
            }
        }
    }
}

// Fused mean-pool + classifier
__global__ __launch_bounds__(64) void k_pool_final(
    const float* __restrict__ feat, const int* __restrict__ batch,
    const float* __restrict__ w, const float* __restrict__ b,
    float* __restrict__ out) {
    int g = blockIdx.x;
    int t = threadIdx.x;
    int o = t & 31, h = t >> 5;
    int lo = 0, hi = NN;
    while (lo < hi) { int mid = (lo + hi) >> 1; if (batch[mid] < g) lo = mid + 1; else hi = mid; }
    int start = lo;
    hi = NN;
    while (lo < hi) { int mid = (lo + hi) >> 1; if (batch[mid] <= g) lo = mid + 1; else hi = mid; }
    int end = lo;
    float acc = 0.f;
    for (int n = start + h; n < end; n += 2) acc += feat[(long)n * 32 + o];
    acc += __shfl_xor(acc, 32, 64);
    float p = acc / fmaxf((float)(end - start), 1.f);
    float l0 = p * w[o], l1 = p * w[32 + o];
#pragma unroll
    for (int s = 16; s >= 1; s >>= 1) {
        l0 += __shfl_xor(l0, s, 64);
        l1 += __shfl_xor(l1, s, 64);
    }
    if (t == 0) {
        l0 += b[0]; l1 += b[1];
        float mx = fmaxf(l0, l1);
        float lse = mx + logf(__expf(l0 - mx) + __expf(l1 - mx));
        out[g * 2 + 0] = l0 - lse;
        out[g * 2 + 1] = l1 - lse;
    }
}

extern "C" void kernel_launch(void* const* d_in, const int* in_sizes, int n_in,
                              void* d_out, int out_size, void* d_ws, size_t ws_size,
                              hipStream_t stream) {
    const float* x        = (const float*)d_in[0];
    const float* edge_attr= (const float*)d_in[1];
    const float* lin0_w   = (const float*)d_in[2];
    const float* lin0_b   = (const float*)d_in[3];
    const float* nn_w     = (const float*)d_in[4];
    const float* nn_b     = (const float*)d_in[5];
    const float* root_w   = (const float*)d_in[6];
    const float* conv_b   = (const float*)d_in[7];
    const float* gru_wi   = (const float*)d_in[8];
    const float* gru_wh   = (const float*)d_in[9];
    const float* gru_bi   = (const float*)d_in[10];
    const float* gru_bh   = (const float*)d_in[11];
    const float* lin1_w   = (const float*)d_in[12];
    const float* lin1_b   = (const float*)d_in[13];
    const int*   edge_idx = (const int*)d_in[14];
    const int*   batch    = (const int*)d_in[15];
    float* out = (float*)d_out;

    // layout: float4 tables first (16B alignment guaranteed at ws base)
    float4* rw4   = (float4*)d_ws;             // 1024
    float4* wi4   = rw4 + 1024;                // 1024
    float4* eea   = wi4 + 1024;                // EE
    float4* oea   = eea + EE;                  // EE
    float*  feat  = (float*)(oea + EE);        // N*32
    float*  Wre   = feat + (long)NN * 32;      // 5120
    int*    cnt   = (int*)(Wre + 5120);        // 2N
    int*    tmp   = cnt + 2 * NN;              // 2N
    int*    bsum  = tmp + 2 * NN;              // 512
    int*    row_ptr = bsum + 512;              // N+1
    int*    cursor  = row_ptr + NN + 1;        // N
    int*    out_ptr = cursor + NN;             // N+1
    int*    cursor2 = out_ptr + NN + 1;        // N
    int*    esrc  = cursor2 + NN;              // EE
    int*    oslot = esrc + EE;                 // EE
    unsigned short* yb   = (unsigned short*)(oslot + EE);  // N*160 bf16
    unsigned short* msgA = yb + (long)NN * 160;            // E*32 bf16
    unsigned short* msgB = msgA + (long)EE * 32;           // E*32 bf16
    const float4* nnw4 = (const float4*)nn_w;  // [1024] rows of 4

    hipMemsetAsync(cnt, 0, 2 * NN * sizeof(int), stream);

    // init + weight tables + histogram (block-partitioned)
    k_setup<<<6250 + 28 + 391, 256, 0, stream>>>(x, lin0_w, lin0_b, nn_w, nn_b,
                                                 root_w, gru_wi, gru_wh, edge_idx,
                                                 feat, Wre, rw4, wi4, cnt);

    k_scan1<<<NB2, 256, 0, stream>>>(cnt, tmp, bsum);
    k_scan2<<<1, 512, 0, stream>>>(bsum);
    k_scan3<<<NB2, 256, 0, stream>>>(cnt, tmp, bsum, row_ptr, cursor, out_ptr, cursor2);

    // scatter + initial y (block-partitioned)
    k_scatter_y<<<391 + 782 * 4, 256, 0, stream>>>(edge_idx, edge_attr, cursor, cursor2,
                                                   esrc, eea, oslot, oea, feat, Wre, yb);

    // 3 fused iterations; iter1 gathers from y, then msg ping-pongs B->A
    k_conv_update<<<(NN + 31) / 32, 256, 0, stream>>>(msgA, row_ptr, rw4, conv_b, wi4,
                                                      gru_bi, gru_bh, nnw4, nn_b,
                                                      out_ptr, oslot, oea,
                                                      yb, esrc, eea,
                                                      feat, msgB, 1, 1);
    k_conv_update<<<(NN + 31) / 32, 256, 0, stream>>>(msgB, row_ptr, rw4, conv_b, wi4,
                                                      gru_bi, gru_bh, nnw4, nn_b,
                                                      out_ptr, oslot, oea,
                                                      yb, esrc, eea,
                                                      feat, msgA, 0, 1);
    k_conv_update<<<(NN + 31) / 32, 256, 0, stream>>>(msgA, row_ptr, rw4, conv_b, wi4,
                                                      gru_bi, gru_bh, nnw4, nn_b,
                                                      out_ptr, oslot, oea,
                                                      yb, esrc, eea,
                                                      feat, msgB, 0, 0);

    k_pool_final<<<GG, 64, 0, stream>>>(feat, batch, lin1_w, lin1_b, out);
}